// Round 1
// baseline (6403.128 us; speedup 1.0000x reference)
//
#include <hip/hip_runtime.h>

#define D 128
#define BN_EPS 1e-5f

// ---------------------------------------------------------------------------
// h0 = sum_f atom_emb[f, x[n,f], :] + z_emb[z[n], :]
// 32 threads per node, float4 per thread.
__global__ void node_init_kernel(const int* __restrict__ x, const int* __restrict__ z,
                                 const float* __restrict__ atom_emb,
                                 const float* __restrict__ z_emb,
                                 float* __restrict__ h, int N) {
    int gid = blockIdx.x * blockDim.x + threadIdx.x;
    int node = gid >> 5;
    if (node >= N) return;
    int d0 = (gid & 31) * 4;
    float4 acc = *(const float4*)(z_emb + (size_t)z[node] * D + d0);
#pragma unroll
    for (int f = 0; f < 9; ++f) {
        int v = x[node * 9 + f];
        const float4 t = *(const float4*)(atom_emb + (size_t)(f * 119 + v) * D + d0);
        acc.x += t.x; acc.y += t.y; acc.z += t.z; acc.w += t.w;
    }
    *(float4*)(h + (size_t)node * D + d0) = acc;
}

// ---------------------------------------------------------------------------
// pre = (1 + eps[l]) * h   (scatter destination pre-init; fuses the GIN self-term)
__global__ void scale_copy_kernel(const float* __restrict__ h, float* __restrict__ pre,
                                  const float* __restrict__ eps_l, int total4) {
    int i = blockIdx.x * blockDim.x + threadIdx.x;
    if (i >= total4) return;
    float s = 1.0f + eps_l[0];
    float4 v = ((const float4*)h)[i];
    v.x *= s; v.y *= s; v.z *= s; v.w *= s;
    ((float4*)pre)[i] = v;
}

// ---------------------------------------------------------------------------
// msg = relu(h[src] + bond_emb(edge_attr)); pre[dst] += msg  (atomic scatter)
// 32 threads per edge, float4 per thread.
__global__ void edge_scatter_kernel(const int* __restrict__ ei, const int* __restrict__ ea,
                                    const float* __restrict__ bond,  // [3,6,D] for this layer
                                    const float* __restrict__ h,
                                    float* __restrict__ pre, int E) {
    int gid = blockIdx.x * blockDim.x + threadIdx.x;
    int e = gid >> 5;
    if (e >= E) return;
    int d0 = (gid & 31) * 4;
    int src = ei[e];
    int dst = ei[E + e];
    int a0 = ea[e * 3 + 0];
    int a1 = ea[e * 3 + 1];
    int a2 = ea[e * 3 + 2];
    const float4 t0 = *(const float4*)(bond + (size_t)(0 * 6 + a0) * D + d0);
    const float4 t1 = *(const float4*)(bond + (size_t)(1 * 6 + a1) * D + d0);
    const float4 t2 = *(const float4*)(bond + (size_t)(2 * 6 + a2) * D + d0);
    const float4 hv = *(const float4*)(h + (size_t)src * D + d0);
    float m0 = fmaxf(hv.x + t0.x + t1.x + t2.x, 0.0f);
    float m1 = fmaxf(hv.y + t0.y + t1.y + t2.y, 0.0f);
    float m2 = fmaxf(hv.z + t0.z + t1.z + t2.z, 0.0f);
    float m3 = fmaxf(hv.w + t0.w + t1.w + t2.w, 0.0f);
    float* p = pre + (size_t)dst * D + d0;
    atomicAdd(p + 0, m0);
    atomicAdd(p + 1, m1);
    atomicAdd(p + 2, m2);
    atomicAdd(p + 3, m3);
}

// ---------------------------------------------------------------------------
// C[M,Ncols] = A'[M,K] @ B[K,Ncols] + bias, where A' = A (TRANSFORM=0) or
// A' = relu(A*tscale[k] + tshift[k]) (TRANSFORM=1: fused BN+ReLU on load).
// 64x64 tile, 256 threads, 4x4 per thread, K chunked by 32.
template <int TRANSFORM>
__global__ __launch_bounds__(256)
void gemm_kernel(const float* __restrict__ A, const float* __restrict__ B,
                 const float* __restrict__ bias, float* __restrict__ C,
                 int M, int K, int Ncols,
                 const float* __restrict__ tscale, const float* __restrict__ tshift) {
    __shared__ float As[32][68];  // [k][m], padded: +4 keeps float4 align, breaks bank conflicts
    __shared__ float Bs[32][64];  // [k][n]
    const int tid = threadIdx.x;
    const int tx = tid & 15;   // col group
    const int ty = tid >> 4;   // row group
    const int m_base = blockIdx.x * 64;
    const int n_base = blockIdx.y * 64;

    float acc[4][4] = {};

    for (int k0 = 0; k0 < K; k0 += 32) {
        // Load A tile (64 rows x 32 k), transposed into LDS.
        {
            const int kk = tid & 31;
            const int r0 = tid >> 5;
            const int k = k0 + kk;
#pragma unroll
            for (int rr = r0; rr < 64; rr += 8) {
                int row = m_base + rr;
                int rc = row < M ? row : (M - 1);
                float v = A[(size_t)rc * K + k];
                if (TRANSFORM) v = fmaxf(v * tscale[k] + tshift[k], 0.0f);
                As[kk][rr] = v;
            }
        }
        // Load B tile (32 k x 64 n).
        {
            const int nn = tid & 63;
            const int ks = tid >> 6;
#pragma unroll
            for (int kk = ks; kk < 32; kk += 4) {
                Bs[kk][nn] = B[(size_t)(k0 + kk) * Ncols + n_base + nn];
            }
        }
        __syncthreads();
#pragma unroll
        for (int kk = 0; kk < 32; ++kk) {
            const float4 a = *(const float4*)&As[kk][ty * 4];
            const float4 b = *(const float4*)&Bs[kk][tx * 4];
            acc[0][0] += a.x * b.x; acc[0][1] += a.x * b.y; acc[0][2] += a.x * b.z; acc[0][3] += a.x * b.w;
            acc[1][0] += a.y * b.x; acc[1][1] += a.y * b.y; acc[1][2] += a.y * b.z; acc[1][3] += a.y * b.w;
            acc[2][0] += a.z * b.x; acc[2][1] += a.z * b.y; acc[2][2] += a.z * b.z; acc[2][3] += a.z * b.w;
            acc[3][0] += a.w * b.x; acc[3][1] += a.w * b.y; acc[3][2] += a.w * b.z; acc[3][3] += a.w * b.w;
        }
        __syncthreads();
    }

    const float4 bv = *(const float4*)(bias + n_base + tx * 4);
#pragma unroll
    for (int i = 0; i < 4; ++i) {
        int row = m_base + ty * 4 + i;
        if (row < M) {
            float4 o;
            o.x = acc[i][0] + bv.x;
            o.y = acc[i][1] + bv.y;
            o.z = acc[i][2] + bv.z;
            o.w = acc[i][3] + bv.w;
            *(float4*)(C + (size_t)row * Ncols + n_base + tx * 4) = o;
        }
    }
}

// ---------------------------------------------------------------------------
// Per-column sum and sum-of-squares over M rows (partials via atomics).
__global__ void colreduce_kernel(const float* __restrict__ X, int M, int C, int logC,
                                 float* __restrict__ sum, float* __restrict__ ss,
                                 int rowsPerBlock) {
    const int tid = threadIdx.x;
    const int j = tid & (C - 1);
    const int roff = tid >> logC;
    const int stride = 256 >> logC;
    const int base = blockIdx.x * rowsPerBlock;
    int end = base + rowsPerBlock;
    if (end > M) end = M;
    float s = 0.0f, q = 0.0f;
    for (int i = base + roff; i < end; i += stride) {
        float v = X[(size_t)i * C + j];
        s += v;
        q += v * v;
    }
    atomicAdd(&sum[j], s);
    atomicAdd(&ss[j], q);
}

// ---------------------------------------------------------------------------
// Fold BN into per-column scale/shift: y = x*scale + shift.
__global__ void finalize_stats_kernel(const float* __restrict__ sum, const float* __restrict__ ss,
                                      const float* __restrict__ g, const float* __restrict__ b,
                                      float* __restrict__ scale, float* __restrict__ shift,
                                      int C, float invN) {
    int j = blockIdx.x * blockDim.x + threadIdx.x;
    if (j >= C) return;
    float mean = sum[j] * invN;
    float var = ss[j] * invN - mean * mean;
    float inv = 1.0f / sqrtf(var + BN_EPS);
    float sc = g[j] * inv;
    scale[j] = sc;
    shift[j] = b[j] - mean * sc;
}

// ---------------------------------------------------------------------------
// h = bn(out2) [+ relu]
__global__ void bn_apply_kernel(const float* __restrict__ X, float* __restrict__ Y,
                                const float* __restrict__ scale, const float* __restrict__ shift,
                                int N, int relu) {
    int gid = blockIdx.x * blockDim.x + threadIdx.x;
    int node = gid >> 5;
    if (node >= N) return;
    int d0 = (gid & 31) * 4;
    float4 v = *(const float4*)(X + (size_t)node * D + d0);
    float4 sc = *(const float4*)(scale + d0);
    float4 sh = *(const float4*)(shift + d0);
    float4 o;
    o.x = v.x * sc.x + sh.x;
    o.y = v.y * sc.y + sh.y;
    o.z = v.z * sc.z + sh.z;
    o.w = v.w * sc.w + sh.w;
    if (relu) {
        o.x = fmaxf(o.x, 0.0f);
        o.y = fmaxf(o.y, 0.0f);
        o.z = fmaxf(o.z, 0.0f);
        o.w = fmaxf(o.w, 0.0f);
    }
    *(float4*)(Y + (size_t)node * D + d0) = o;
}

// ---------------------------------------------------------------------------
extern "C" void kernel_launch(void* const* d_in, const int* in_sizes, int n_in,
                              void* d_out, int out_size, void* d_ws, size_t ws_size,
                              hipStream_t stream) {
    const int*   x        = (const int*)d_in[0];
    const int*   z        = (const int*)d_in[1];
    const int*   ei       = (const int*)d_in[2];
    const int*   ea       = (const int*)d_in[3];
    const float* atom_emb = (const float*)d_in[4];
    const float* z_emb    = (const float*)d_in[5];
    const float* bond_emb = (const float*)d_in[6];
    const float* eps      = (const float*)d_in[7];
    const float* W1       = (const float*)d_in[8];
    const float* b1       = (const float*)d_in[9];
    const float* g1       = (const float*)d_in[10];
    const float* be1      = (const float*)d_in[11];
    const float* W2       = (const float*)d_in[12];
    const float* b2       = (const float*)d_in[13];
    const float* bng      = (const float*)d_in[14];
    const float* bnb      = (const float*)d_in[15];

    const int N = in_sizes[1];
    const int E = in_sizes[3] / 3;

    float* h = (float*)d_out;  // [N,128] — h lives in d_out across layers.

    char* ws = (char*)d_ws;
    float* pre  = (float*)ws;                                   // N*128 floats
    float* out1 = (float*)(ws + (size_t)N * D * sizeof(float)); // N*256 floats
    float* stats = (float*)(ws + (size_t)N * D * sizeof(float) + (size_t)N * 2 * D * sizeof(float));
    float* sum1 = stats;            // 256
    float* ss1  = stats + 256;      // 256
    float* sum2 = stats + 512;      // 128
    float* ss2  = stats + 640;      // 128
    float* scale1 = stats + 768;    // 256
    float* shift1 = stats + 1024;   // 256
    float* scale2 = stats + 1280;   // 128
    float* shift2 = stats + 1408;   // 128
    float* out2 = pre;              // reuse: pre dead after GEMM1 reads it

    const float invN = 1.0f / (float)N;

    node_init_kernel<<<(N * 32 + 255) / 256, 256, 0, stream>>>(x, z, atom_emb, z_emb, h, N);

    for (int l = 0; l < 2; ++l) {
        const float* bond_l = bond_emb + (size_t)l * 3 * 6 * D;

        scale_copy_kernel<<<(N * 32 + 255) / 256, 256, 0, stream>>>(h, pre, eps + l, N * 32);
        edge_scatter_kernel<<<(E * 32 + 255) / 256, 256, 0, stream>>>(ei, ea, bond_l, h, pre, E);

        hipMemsetAsync(stats, 0, 768 * sizeof(float), stream);

        dim3 grid1((N + 63) / 64, 4);
        gemm_kernel<0><<<grid1, 256, 0, stream>>>(pre, W1 + (size_t)l * D * 2 * D,
                                                  b1 + (size_t)l * 2 * D, out1,
                                                  N, D, 2 * D, nullptr, nullptr);
        colreduce_kernel<<<(N + 127) / 128, 256, 0, stream>>>(out1, N, 256, 8, sum1, ss1, 128);
        finalize_stats_kernel<<<1, 256, 0, stream>>>(sum1, ss1, g1 + (size_t)l * 2 * D,
                                                     be1 + (size_t)l * 2 * D, scale1, shift1,
                                                     256, invN);

        dim3 grid2((N + 63) / 64, 2);
        gemm_kernel<1><<<grid2, 256, 0, stream>>>(out1, W2 + (size_t)l * 2 * D * D,
                                                  b2 + (size_t)l * D, out2,
                                                  N, 2 * D, D, scale1, shift1);
        colreduce_kernel<<<(N + 127) / 128, 256, 0, stream>>>(out2, N, 128, 7, sum2, ss2, 128);
        finalize_stats_kernel<<<1, 128, 0, stream>>>(sum2, ss2, bng + (size_t)l * D,
                                                     bnb + (size_t)l * D, scale2, shift2,
                                                     128, invN);

        bn_apply_kernel<<<(N * 32 + 255) / 256, 256, 0, stream>>>(out2, h, scale2, shift2,
                                                                  N, l == 0 ? 1 : 0);
    }
}

// Round 2
// 1465.522 us; speedup vs baseline: 4.3692x; 4.3692x over previous
//
#include <hip/hip_runtime.h>

#define D 128
#define BN_EPS 1e-5f

// ---------------------------------------------------------------------------
// h0 = sum_f atom_emb[f, x[n,f], :] + z_emb[z[n], :]
__global__ void node_init_kernel(const int* __restrict__ x, const int* __restrict__ z,
                                 const float* __restrict__ atom_emb,
                                 const float* __restrict__ z_emb,
                                 float* __restrict__ h, int N) {
    int gid = blockIdx.x * blockDim.x + threadIdx.x;
    int node = gid >> 5;
    if (node >= N) return;
    int d0 = (gid & 31) * 4;
    float4 acc = *(const float4*)(z_emb + (size_t)z[node] * D + d0);
#pragma unroll
    for (int f = 0; f < 9; ++f) {
        int v = x[node * 9 + f];
        const float4 t = *(const float4*)(atom_emb + (size_t)(f * 119 + v) * D + d0);
        acc.x += t.x; acc.y += t.y; acc.z += t.z; acc.w += t.w;
    }
    *(float4*)(h + (size_t)node * D + d0) = acc;
}

// ---------------------------------------------------------------------------
// CSR build step 1: in-degree histogram.
__global__ void histogram_kernel(const int* __restrict__ ei, int* __restrict__ counts, int E) {
    int e = blockIdx.x * blockDim.x + threadIdx.x;
    if (e >= E) return;
    atomicAdd(&counts[ei[E + e]], 1);
}

// ---------------------------------------------------------------------------
// CSR build step 2: exclusive scan of counts -> offsets[N+1]. Single block,
// 1024 threads, 4 elems/thread per chunk, shuffle scan (wave=64).
__global__ __launch_bounds__(1024)
void scan_kernel(const int* __restrict__ counts, int* __restrict__ offsets, int N) {
    __shared__ int wsum[16];
    __shared__ int carry_s;
    const int tid = threadIdx.x;
    const int lane = tid & 63, wid = tid >> 6;
    if (tid == 0) { carry_s = 0; offsets[0] = 0; }
    __syncthreads();
    for (int base = 0; base < N; base += 4096) {
        int idx = base + tid * 4;
        int4 c = {0, 0, 0, 0};
        if (idx + 3 < N) {
            c = *(const int4*)(counts + idx);
        } else {
            if (idx + 0 < N) c.x = counts[idx + 0];
            if (idx + 1 < N) c.y = counts[idx + 1];
            if (idx + 2 < N) c.z = counts[idx + 2];
            if (idx + 3 < N) c.w = counts[idx + 3];
        }
        int p1 = c.x, p2 = p1 + c.y, p3 = p2 + c.z, p4 = p3 + c.w;
        int s = p4;
#pragma unroll
        for (int off = 1; off < 64; off <<= 1) {
            int t = __shfl_up(s, off, 64);
            if (lane >= off) s += t;
        }
        if (lane == 63) wsum[wid] = s;
        __syncthreads();
        int carry = carry_s;
        if (wid == 0) {
            int w = (lane < 16) ? wsum[lane] : 0;
#pragma unroll
            for (int off = 1; off < 16; off <<= 1) {
                int t = __shfl_up(w, off, 64);
                if (lane >= off) w += t;
            }
            if (lane < 16) wsum[lane] = w;  // inclusive wave-sums scan
        }
        __syncthreads();
        int wbase = (wid > 0) ? wsum[wid - 1] : 0;
        int excl = carry + wbase + (s - p4);
        if (idx + 0 < N) offsets[idx + 1] = excl + p1;
        if (idx + 1 < N) offsets[idx + 2] = excl + p2;
        if (idx + 2 < N) offsets[idx + 3] = excl + p3;
        if (idx + 3 < N) offsets[idx + 4] = excl + p4;
        __syncthreads();
        if (tid == 1023) carry_s = carry + wsum[15];
        __syncthreads();
    }
}

// ---------------------------------------------------------------------------
// CSR build step 3: scatter packed (src | a0<<17 | a1<<20 | a2<<23) into buckets.
__global__ void fill_kernel(const int* __restrict__ ei, const int* __restrict__ ea,
                            const int* __restrict__ offsets, int* __restrict__ cursor,
                            int* __restrict__ bucket, int E) {
    int e = blockIdx.x * blockDim.x + threadIdx.x;
    if (e >= E) return;
    int dst = ei[E + e];
    int src = ei[e];
    int a0 = ea[e * 3 + 0], a1 = ea[e * 3 + 1], a2 = ea[e * 3 + 2];
    int pos = offsets[dst] + atomicAdd(&cursor[dst], 1);
    bucket[pos] = src | (a0 << 17) | (a1 << 20) | (a2 << 23);
}

// ---------------------------------------------------------------------------
// pre[n] = (1+eps)*h[n] + sum_{e in in(n)} relu(h[src_e] + bond(edge_attr_e))
// 32 lanes per node, float4/lane; bond tables staged in LDS (9 KB).
__global__ __launch_bounds__(256)
void gather_reduce_kernel(const int* __restrict__ offsets, const int* __restrict__ bucket,
                          const float* __restrict__ bond,  // [3,6,D] this layer
                          const float* __restrict__ h,
                          const float* __restrict__ eps_l,
                          float* __restrict__ pre, int N) {
    __shared__ float sbond[3 * 6 * D];
    for (int i = threadIdx.x; i < 3 * 6 * D; i += 256) sbond[i] = bond[i];
    __syncthreads();

    int gid = blockIdx.x * blockDim.x + threadIdx.x;
    int node = gid >> 5;
    if (node >= N) return;
    int d0 = (gid & 31) * 4;

    float s = 1.0f + eps_l[0];
    float4 hv = *(const float4*)(h + (size_t)node * D + d0);
    float4 acc = make_float4(hv.x * s, hv.y * s, hv.z * s, hv.w * s);

    int beg = offsets[node], end = offsets[node + 1];
    for (int p = beg; p < end; ++p) {
        int pk = bucket[p];
        int src = pk & 0x1FFFF;
        int a0 = (pk >> 17) & 7, a1 = (pk >> 20) & 7, a2 = (pk >> 23) & 7;
        const float4 sv = *(const float4*)(h + (size_t)src * D + d0);
        const float4 b0 = *(const float4*)&sbond[(0 * 6 + a0) * D + d0];
        const float4 b1 = *(const float4*)&sbond[(1 * 6 + a1) * D + d0];
        const float4 b2 = *(const float4*)&sbond[(2 * 6 + a2) * D + d0];
        acc.x += fmaxf(sv.x + b0.x + b1.x + b2.x, 0.0f);
        acc.y += fmaxf(sv.y + b0.y + b1.y + b2.y, 0.0f);
        acc.z += fmaxf(sv.z + b0.z + b1.z + b2.z, 0.0f);
        acc.w += fmaxf(sv.w + b0.w + b1.w + b2.w, 0.0f);
    }
    *(float4*)(pre + (size_t)node * D + d0) = acc;
}

// ---------------------------------------------------------------------------
// C[M,Ncols] = A'[M,K] @ B[K,Ncols] + bias; TRANSFORM=1 applies relu(A*sc+sh).
template <int TRANSFORM>
__global__ __launch_bounds__(256)
void gemm_kernel(const float* __restrict__ A, const float* __restrict__ B,
                 const float* __restrict__ bias, float* __restrict__ C,
                 int M, int K, int Ncols,
                 const float* __restrict__ tscale, const float* __restrict__ tshift) {
    __shared__ float As[32][68];
    __shared__ float Bs[32][64];
    const int tid = threadIdx.x;
    const int tx = tid & 15;
    const int ty = tid >> 4;
    const int m_base = blockIdx.x * 64;
    const int n_base = blockIdx.y * 64;

    float acc[4][4] = {};

    for (int k0 = 0; k0 < K; k0 += 32) {
        {
            const int kk = tid & 31;
            const int r0 = tid >> 5;
            const int k = k0 + kk;
#pragma unroll
            for (int rr = r0; rr < 64; rr += 8) {
                int row = m_base + rr;
                int rc = row < M ? row : (M - 1);
                float v = A[(size_t)rc * K + k];
                if (TRANSFORM) v = fmaxf(v * tscale[k] + tshift[k], 0.0f);
                As[kk][rr] = v;
            }
        }
        {
            const int nn = tid & 63;
            const int ks = tid >> 6;
#pragma unroll
            for (int kk = ks; kk < 32; kk += 4) {
                Bs[kk][nn] = B[(size_t)(k0 + kk) * Ncols + n_base + nn];
            }
        }
        __syncthreads();
#pragma unroll
        for (int kk = 0; kk < 32; ++kk) {
            const float4 a = *(const float4*)&As[kk][ty * 4];
            const float4 b = *(const float4*)&Bs[kk][tx * 4];
            acc[0][0] += a.x * b.x; acc[0][1] += a.x * b.y; acc[0][2] += a.x * b.z; acc[0][3] += a.x * b.w;
            acc[1][0] += a.y * b.x; acc[1][1] += a.y * b.y; acc[1][2] += a.y * b.z; acc[1][3] += a.y * b.w;
            acc[2][0] += a.z * b.x; acc[2][1] += a.z * b.y; acc[2][2] += a.z * b.z; acc[2][3] += a.z * b.w;
            acc[3][0] += a.w * b.x; acc[3][1] += a.w * b.y; acc[3][2] += a.w * b.z; acc[3][3] += a.w * b.w;
        }
        __syncthreads();
    }

    const float4 bv = *(const float4*)(bias + n_base + tx * 4);
#pragma unroll
    for (int i = 0; i < 4; ++i) {
        int row = m_base + ty * 4 + i;
        if (row < M) {
            float4 o;
            o.x = acc[i][0] + bv.x;
            o.y = acc[i][1] + bv.y;
            o.z = acc[i][2] + bv.z;
            o.w = acc[i][3] + bv.w;
            *(float4*)(C + (size_t)row * Ncols + n_base + tx * 4) = o;
        }
    }
}

// ---------------------------------------------------------------------------
__global__ void colreduce_kernel(const float* __restrict__ X, int M, int C, int logC,
                                 float* __restrict__ sum, float* __restrict__ ss,
                                 int rowsPerBlock) {
    const int tid = threadIdx.x;
    const int j = tid & (C - 1);
    const int roff = tid >> logC;
    const int stride = 256 >> logC;
    const int base = blockIdx.x * rowsPerBlock;
    int end = base + rowsPerBlock;
    if (end > M) end = M;
    float s = 0.0f, q = 0.0f;
    for (int i = base + roff; i < end; i += stride) {
        float v = X[(size_t)i * C + j];
        s += v;
        q += v * v;
    }
    atomicAdd(&sum[j], s);
    atomicAdd(&ss[j], q);
}

// ---------------------------------------------------------------------------
__global__ void finalize_stats_kernel(const float* __restrict__ sum, const float* __restrict__ ss,
                                      const float* __restrict__ g, const float* __restrict__ b,
                                      float* __restrict__ scale, float* __restrict__ shift,
                                      int C, float invN) {
    int j = blockIdx.x * blockDim.x + threadIdx.x;
    if (j >= C) return;
    float mean = sum[j] * invN;
    float var = ss[j] * invN - mean * mean;
    float inv = 1.0f / sqrtf(var + BN_EPS);
    float sc = g[j] * inv;
    scale[j] = sc;
    shift[j] = b[j] - mean * sc;
}

// ---------------------------------------------------------------------------
__global__ void bn_apply_kernel(const float* __restrict__ X, float* __restrict__ Y,
                                const float* __restrict__ scale, const float* __restrict__ shift,
                                int N, int relu) {
    int gid = blockIdx.x * blockDim.x + threadIdx.x;
    int node = gid >> 5;
    if (node >= N) return;
    int d0 = (gid & 31) * 4;
    float4 v = *(const float4*)(X + (size_t)node * D + d0);
    float4 sc = *(const float4*)(scale + d0);
    float4 sh = *(const float4*)(shift + d0);
    float4 o;
    o.x = v.x * sc.x + sh.x;
    o.y = v.y * sc.y + sh.y;
    o.z = v.z * sc.z + sh.z;
    o.w = v.w * sc.w + sh.w;
    if (relu) {
        o.x = fmaxf(o.x, 0.0f);
        o.y = fmaxf(o.y, 0.0f);
        o.z = fmaxf(o.z, 0.0f);
        o.w = fmaxf(o.w, 0.0f);
    }
    *(float4*)(Y + (size_t)node * D + d0) = o;
}

// ---------------------------------------------------------------------------
extern "C" void kernel_launch(void* const* d_in, const int* in_sizes, int n_in,
                              void* d_out, int out_size, void* d_ws, size_t ws_size,
                              hipStream_t stream) {
    const int*   x        = (const int*)d_in[0];
    const int*   z        = (const int*)d_in[1];
    const int*   ei       = (const int*)d_in[2];
    const int*   ea       = (const int*)d_in[3];
    const float* atom_emb = (const float*)d_in[4];
    const float* z_emb    = (const float*)d_in[5];
    const float* bond_emb = (const float*)d_in[6];
    const float* eps      = (const float*)d_in[7];
    const float* W1       = (const float*)d_in[8];
    const float* b1       = (const float*)d_in[9];
    const float* g1       = (const float*)d_in[10];
    const float* be1      = (const float*)d_in[11];
    const float* W2       = (const float*)d_in[12];
    const float* b2       = (const float*)d_in[13];
    const float* bng      = (const float*)d_in[14];
    const float* bnb      = (const float*)d_in[15];

    const int N = in_sizes[1];
    const int E = in_sizes[3] / 3;

    float* h = (float*)d_out;  // [N,128]

    char* ws = (char*)d_ws;
    size_t off = 0;
    float* pre  = (float*)(ws + off); off += (size_t)N * D * sizeof(float);        // 51.2 MB
    float* out1 = (float*)(ws + off); off += (size_t)N * 2 * D * sizeof(float);    // 102.4 MB
    float* stats = (float*)(ws + off); off += 1536 * sizeof(float);
    int* offsets = (int*)(ws + off); off += (size_t)(N + 1) * sizeof(int);
    int* bucket  = (int*)(ws + off); off += (size_t)E * sizeof(int);
    // transient (only live before GEMM1 first writes out1):
    int* counts = (int*)out1;
    int* cursor = (int*)out1 + N;

    float* sum1 = stats;            // 256
    float* ss1  = stats + 256;      // 256
    float* sum2 = stats + 512;      // 128
    float* ss2  = stats + 640;      // 128
    float* scale1 = stats + 768;    // 256
    float* shift1 = stats + 1024;   // 256
    float* scale2 = stats + 1280;   // 128
    float* shift2 = stats + 1408;   // 128
    float* out2 = pre;              // reuse: pre dead after GEMM1 reads it

    const float invN = 1.0f / (float)N;

    // --- CSR build (graph is layer-invariant: build once) ---
    hipMemsetAsync(counts, 0, (size_t)N * 2 * sizeof(int), stream);  // counts+cursor
    histogram_kernel<<<(E + 255) / 256, 256, 0, stream>>>(ei, counts, E);
    scan_kernel<<<1, 1024, 0, stream>>>(counts, offsets, N);
    fill_kernel<<<(E + 255) / 256, 256, 0, stream>>>(ei, ea, offsets, cursor, bucket, E);

    node_init_kernel<<<(N * 32 + 255) / 256, 256, 0, stream>>>(x, z, atom_emb, z_emb, h, N);

    for (int l = 0; l < 2; ++l) {
        const float* bond_l = bond_emb + (size_t)l * 3 * 6 * D;

        gather_reduce_kernel<<<(N * 32 + 255) / 256, 256, 0, stream>>>(
            offsets, bucket, bond_l, h, eps + l, pre, N);

        hipMemsetAsync(stats, 0, 768 * sizeof(float), stream);

        dim3 grid1((N + 63) / 64, 4);
        gemm_kernel<0><<<grid1, 256, 0, stream>>>(pre, W1 + (size_t)l * D * 2 * D,
                                                  b1 + (size_t)l * 2 * D, out1,
                                                  N, D, 2 * D, nullptr, nullptr);
        colreduce_kernel<<<(N + 127) / 128, 256, 0, stream>>>(out1, N, 256, 8, sum1, ss1, 128);
        finalize_stats_kernel<<<1, 256, 0, stream>>>(sum1, ss1, g1 + (size_t)l * 2 * D,
                                                     be1 + (size_t)l * 2 * D, scale1, shift1,
                                                     256, invN);

        dim3 grid2((N + 63) / 64, 2);
        gemm_kernel<1><<<grid2, 256, 0, stream>>>(out1, W2 + (size_t)l * 2 * D * D,
                                                  b2 + (size_t)l * D, out2,
                                                  N, 2 * D, D, scale1, shift1);
        colreduce_kernel<<<(N + 127) / 128, 256, 0, stream>>>(out2, N, 128, 7, sum2, ss2, 128);
        finalize_stats_kernel<<<1, 128, 0, stream>>>(sum2, ss2, bng + (size_t)l * D,
                                                     bnb + (size_t)l * D, scale2, shift2,
                                                     128, invN);

        bn_apply_kernel<<<(N * 32 + 255) / 256, 256, 0, stream>>>(out2, h, scale2, shift2,
                                                                  N, l == 0 ? 1 : 0);
    }
}

// Round 3
// 970.021 us; speedup vs baseline: 6.6010x; 1.5108x over previous
//
#include <hip/hip_runtime.h>

#define D 128
#define BN_EPS 1e-5f

typedef __attribute__((ext_vector_type(8))) short short8;   // 8 x bf16 (4 VGPRs)
typedef __attribute__((ext_vector_type(4))) float floatx4;  // MFMA accumulator

__device__ __forceinline__ float bf2f(unsigned short u) {
    unsigned int x = ((unsigned int)u) << 16;
    return __builtin_bit_cast(float, x);
}
__device__ __forceinline__ unsigned short f2bf(float f) {
    unsigned int x = __builtin_bit_cast(unsigned int, f);
    x = x + 0x7FFFu + ((x >> 16) & 1u);  // round-to-nearest-even
    return (unsigned short)(x >> 16);
}

// ---------------------------------------------------------------------------
// hb0 = bf16( sum_f atom_emb[f, x[n,f], :] + z_emb[z[n], :] )
__global__ void node_init_kernel(const int* __restrict__ x, const int* __restrict__ z,
                                 const float* __restrict__ atom_emb,
                                 const float* __restrict__ z_emb,
                                 unsigned short* __restrict__ hb, int N) {
    int gid = blockIdx.x * blockDim.x + threadIdx.x;
    int node = gid >> 5;
    if (node >= N) return;
    int d0 = (gid & 31) * 4;
    float4 acc = *(const float4*)(z_emb + (size_t)z[node] * D + d0);
#pragma unroll
    for (int f = 0; f < 9; ++f) {
        int v = x[node * 9 + f];
        const float4 t = *(const float4*)(atom_emb + (size_t)(f * 119 + v) * D + d0);
        acc.x += t.x; acc.y += t.y; acc.z += t.z; acc.w += t.w;
    }
    ushort4 o;
    o.x = f2bf(acc.x); o.y = f2bf(acc.y); o.z = f2bf(acc.z); o.w = f2bf(acc.w);
    *(ushort4*)(hb + (size_t)node * D + d0) = o;
}

// ---------------------------------------------------------------------------
// CSR build
__global__ void histogram_kernel(const int* __restrict__ ei, int* __restrict__ counts, int E) {
    int e = blockIdx.x * blockDim.x + threadIdx.x;
    if (e >= E) return;
    atomicAdd(&counts[ei[E + e]], 1);
}

__global__ __launch_bounds__(1024)
void scan_kernel(const int* __restrict__ counts, int* __restrict__ offsets, int N) {
    __shared__ int wsum[16];
    __shared__ int carry_s;
    const int tid = threadIdx.x;
    const int lane = tid & 63, wid = tid >> 6;
    if (tid == 0) { carry_s = 0; offsets[0] = 0; }
    __syncthreads();
    for (int base = 0; base < N; base += 4096) {
        int idx = base + tid * 4;
        int4 c = {0, 0, 0, 0};
        if (idx + 3 < N) {
            c = *(const int4*)(counts + idx);
        } else {
            if (idx + 0 < N) c.x = counts[idx + 0];
            if (idx + 1 < N) c.y = counts[idx + 1];
            if (idx + 2 < N) c.z = counts[idx + 2];
            if (idx + 3 < N) c.w = counts[idx + 3];
        }
        int p1 = c.x, p2 = p1 + c.y, p3 = p2 + c.z, p4 = p3 + c.w;
        int s = p4;
#pragma unroll
        for (int off = 1; off < 64; off <<= 1) {
            int t = __shfl_up(s, off, 64);
            if (lane >= off) s += t;
        }
        if (lane == 63) wsum[wid] = s;
        __syncthreads();
        int carry = carry_s;
        if (wid == 0) {
            int w = (lane < 16) ? wsum[lane] : 0;
#pragma unroll
            for (int off = 1; off < 16; off <<= 1) {
                int t = __shfl_up(w, off, 64);
                if (lane >= off) w += t;
            }
            if (lane < 16) wsum[lane] = w;
        }
        __syncthreads();
        int wbase = (wid > 0) ? wsum[wid - 1] : 0;
        int excl = carry + wbase + (s - p4);
        if (idx + 0 < N) offsets[idx + 1] = excl + p1;
        if (idx + 1 < N) offsets[idx + 2] = excl + p2;
        if (idx + 2 < N) offsets[idx + 3] = excl + p3;
        if (idx + 3 < N) offsets[idx + 4] = excl + p4;
        __syncthreads();
        if (tid == 1023) carry_s = carry + wsum[15];
        __syncthreads();
    }
}

// bucket word: src (17 bits) | comb_idx << 17 (8 bits), comb_idx = (a0*6+a1)*6+a2
__global__ void fill_kernel(const int* __restrict__ ei, const int* __restrict__ ea,
                            const int* __restrict__ offsets, int* __restrict__ cursor,
                            int* __restrict__ bucket, int E) {
    int e = blockIdx.x * blockDim.x + threadIdx.x;
    if (e >= E) return;
    int dst = ei[E + e];
    int src = ei[e];
    int c = (ea[e * 3 + 0] * 6 + ea[e * 3 + 1]) * 6 + ea[e * 3 + 2];
    int pos = offsets[dst] + atomicAdd(&cursor[dst], 1);
    bucket[pos] = src | (c << 17);
}

// ---------------------------------------------------------------------------
// comb[layer][c][d] = bf16( b0[a0][d] + b1[a1][d] + b2[a2][d] ),  c=(a0*6+a1)*6+a2
__global__ void comb_kernel(const float* __restrict__ bond_emb, unsigned short* __restrict__ comb) {
    int idx = blockIdx.x * 256 + threadIdx.x;  // c*128 + d
    if (idx >= 216 * D) return;
    int c = idx >> 7, d = idx & 127;
    int a0 = c / 36, a1 = (c / 6) % 6, a2 = c % 6;
    const float* b = bond_emb + (size_t)blockIdx.y * 3 * 6 * D;
    float v = b[(0 * 6 + a0) * D + d] + b[(1 * 6 + a1) * D + d] + b[(2 * 6 + a2) * D + d];
    comb[(size_t)blockIdx.y * 216 * D + idx] = f2bf(v);
}

// ---------------------------------------------------------------------------
// Pack W [K][NCOLS] fp32 row-major -> Wp[k/32][n][k%32] bf16 (MFMA B-fragment order).
__global__ void pack_w_kernel(const float* __restrict__ W, unsigned short* __restrict__ Wp,
                              int total, int logN) {
    int idx = blockIdx.x * 256 + threadIdx.x;
    if (idx >= total) return;
    int NCOLS = 1 << logN;
    int k = idx >> logN, n = idx & (NCOLS - 1);
    const float* Wl = W + (size_t)blockIdx.y * total;
    unsigned short* Wpl = Wp + (size_t)blockIdx.y * total;
    Wpl[((size_t)(k >> 5) * NCOLS + n) * 32 + (k & 31)] = f2bf(Wl[idx]);
}

// ---------------------------------------------------------------------------
// pre[n] = bf16( (1+eps)*h[n] + sum_{e in in(n)} relu(h[src_e] + comb[c_e]) )
// 16 lanes per node, 8 elems/lane (16 B bf16 loads).
__global__ __launch_bounds__(256)
void gather_reduce_kernel(const int* __restrict__ offsets, const int* __restrict__ bucket,
                          const unsigned short* __restrict__ comb,  // [216][D] this layer
                          const unsigned short* __restrict__ hb,
                          const float* __restrict__ eps_l,
                          unsigned short* __restrict__ pre, int N) {
    int gid = blockIdx.x * blockDim.x + threadIdx.x;
    int node = gid >> 4;
    if (node >= N) return;
    int d0 = (gid & 15) * 8;

    union U8 { int4 i; unsigned short u[8]; };
    float s = 1.0f + eps_l[0];
    float a[8];
    {
        U8 hv; hv.i = *(const int4*)(hb + (size_t)node * D + d0);
#pragma unroll
        for (int j = 0; j < 8; ++j) a[j] = bf2f(hv.u[j]) * s;
    }
    int beg = offsets[node], end = offsets[node + 1];
    for (int p = beg; p < end; ++p) {
        int pk = bucket[p];
        int src = pk & 0x1FFFF;
        int c = (pk >> 17) & 0xFF;
        U8 hv, cv;
        hv.i = *(const int4*)(hb + (size_t)src * D + d0);
        cv.i = *(const int4*)(comb + (size_t)c * D + d0);
#pragma unroll
        for (int j = 0; j < 8; ++j)
            a[j] += fmaxf(bf2f(hv.u[j]) + bf2f(cv.u[j]), 0.0f);
    }
    U8 o;
#pragma unroll
    for (int j = 0; j < 8; ++j) o.u[j] = f2bf(a[j]);
    *(int4*)(pre + (size_t)node * D + d0) = o.i;
}

// ---------------------------------------------------------------------------
// MFMA GEMM: C[M,NCOLS] = A'[M,K] @ W[K,NCOLS] + bias.
// A bf16 row-major; Wp packed B-fragments; TRANSFORM: A' = bf16(relu(A*sc+sh)).
// Block = 4 waves; wave w handles rows [blk*64 + w*16, +16), ALL n-tiles in regs.
template <int K, int NCOLS, int TRANSFORM, int OUTBF>
__global__ __launch_bounds__(256)
void mfma_gemm_kernel(const unsigned short* __restrict__ A,
                      const unsigned short* __restrict__ Wp,
                      const float* __restrict__ bias,
                      const float* __restrict__ tscale, const float* __restrict__ tshift,
                      unsigned short* __restrict__ Cbf, float* __restrict__ Cf, int M) {
    constexpr int NT = NCOLS / 16;
    const int tid = threadIdx.x;
    const int wave = tid >> 6, lane = tid & 63;
    const int q = lane >> 4, ln = lane & 15;
    const int m_base = blockIdx.x * 64 + wave * 16;
    int arow = m_base + ln;
    if (arow >= M) arow = M - 1;
    const int kq = q * 8;

    floatx4 acc[NT];
#pragma unroll
    for (int t = 0; t < NT; ++t) acc[t] = (floatx4){0.f, 0.f, 0.f, 0.f};

#pragma unroll
    for (int k0 = 0; k0 < K; k0 += 32) {
        short8 afrag;
        if constexpr (TRANSFORM) {
            union { int4 i; unsigned short u[8]; } raw;
            raw.i = *(const int4*)(A + (size_t)arow * K + k0 + kq);
            float4 sc0 = *(const float4*)(tscale + k0 + kq);
            float4 sc1 = *(const float4*)(tscale + k0 + kq + 4);
            float4 sh0 = *(const float4*)(tshift + k0 + kq);
            float4 sh1 = *(const float4*)(tshift + k0 + kq + 4);
            union { short8 v; unsigned short u[8]; } au;
            au.u[0] = f2bf(fmaxf(bf2f(raw.u[0]) * sc0.x + sh0.x, 0.f));
            au.u[1] = f2bf(fmaxf(bf2f(raw.u[1]) * sc0.y + sh0.y, 0.f));
            au.u[2] = f2bf(fmaxf(bf2f(raw.u[2]) * sc0.z + sh0.z, 0.f));
            au.u[3] = f2bf(fmaxf(bf2f(raw.u[3]) * sc0.w + sh0.w, 0.f));
            au.u[4] = f2bf(fmaxf(bf2f(raw.u[4]) * sc1.x + sh1.x, 0.f));
            au.u[5] = f2bf(fmaxf(bf2f(raw.u[5]) * sc1.y + sh1.y, 0.f));
            au.u[6] = f2bf(fmaxf(bf2f(raw.u[6]) * sc1.z + sh1.z, 0.f));
            au.u[7] = f2bf(fmaxf(bf2f(raw.u[7]) * sc1.w + sh1.w, 0.f));
            afrag = au.v;
        } else {
            afrag = *(const short8*)(A + (size_t)arow * K + k0 + kq);
        }
#pragma unroll
        for (int t = 0; t < NT; ++t) {
            short8 bfrag = *(const short8*)(Wp + ((size_t)(k0 >> 5) * NCOLS + (t * 16 + ln)) * 32 + kq);
            acc[t] = __builtin_amdgcn_mfma_f32_16x16x32_bf16(afrag, bfrag, acc[t], 0, 0, 0);
        }
    }

#pragma unroll
    for (int t = 0; t < NT; ++t) {
        int col = t * 16 + ln;
        float bv = bias[col];
#pragma unroll
        for (int r = 0; r < 4; ++r) {
            int row = m_base + q * 4 + r;
            if (row < M) {
                float v = acc[t][r] + bv;
                if constexpr (OUTBF) Cbf[(size_t)row * NCOLS + col] = f2bf(v);
                else                 Cf[(size_t)row * NCOLS + col] = v;
            }
        }
    }
}

// ---------------------------------------------------------------------------
// Column sums / sum-of-squares, bf16 input, 256 columns (thread = column).
__global__ void colreduce_bf_kernel(const unsigned short* __restrict__ X, int M,
                                    float* __restrict__ sum, float* __restrict__ ss,
                                    int rowsPerBlock) {
    const int j = threadIdx.x;
    const int base = blockIdx.x * rowsPerBlock;
    int end = base + rowsPerBlock;
    if (end > M) end = M;
    float s = 0.0f, q = 0.0f;
    for (int i = base; i < end; ++i) {
        float v = bf2f(X[(size_t)i * 256 + j]);
        s += v;
        q += v * v;
    }
    atomicAdd(&sum[j], s);
    atomicAdd(&ss[j], q);
}

// fp32 input, C columns (power of 2).
__global__ void colreduce_f32_kernel(const float* __restrict__ X, int M, int C, int logC,
                                     float* __restrict__ sum, float* __restrict__ ss,
                                     int rowsPerBlock) {
    const int tid = threadIdx.x;
    const int j = tid & (C - 1);
    const int roff = tid >> logC;
    const int stride = 256 >> logC;
    const int base = blockIdx.x * rowsPerBlock;
    int end = base + rowsPerBlock;
    if (end > M) end = M;
    float s = 0.0f, q = 0.0f;
    for (int i = base + roff; i < end; i += stride) {
        float v = X[(size_t)i * C + j];
        s += v;
        q += v * v;
    }
    atomicAdd(&sum[j], s);
    atomicAdd(&ss[j], q);
}

// ---------------------------------------------------------------------------
__global__ void finalize_stats_kernel(const float* __restrict__ sum, const float* __restrict__ ss,
                                      const float* __restrict__ g, const float* __restrict__ b,
                                      float* __restrict__ scale, float* __restrict__ shift,
                                      int C, float invN) {
    int j = blockIdx.x * blockDim.x + threadIdx.x;
    if (j >= C) return;
    float mean = sum[j] * invN;
    float var = ss[j] * invN - mean * mean;
    float inv = 1.0f / sqrtf(var + BN_EPS);
    float sc = g[j] * inv;
    scale[j] = sc;
    shift[j] = b[j] - mean * sc;
}

// ---------------------------------------------------------------------------
// mode 0: hb = bf16(relu(bn(out2)))   (layer 0 -> feeds next gather)
// mode 1: h  = bn(out2)  fp32         (layer 1 -> final output)
__global__ void bn_apply_kernel(const float* __restrict__ X, float* __restrict__ Yf,
                                unsigned short* __restrict__ Yb,
                                const float* __restrict__ scale, const float* __restrict__ shift,
                                int N, int mode) {
    int gid = blockIdx.x * blockDim.x + threadIdx.x;
    int node = gid >> 5;
    if (node >= N) return;
    int d0 = (gid & 31) * 4;
    float4 v = *(const float4*)(X + (size_t)node * D + d0);
    float4 sc = *(const float4*)(scale + d0);
    float4 sh = *(const float4*)(shift + d0);
    float4 o;
    o.x = v.x * sc.x + sh.x;
    o.y = v.y * sc.y + sh.y;
    o.z = v.z * sc.z + sh.z;
    o.w = v.w * sc.w + sh.w;
    if (mode == 0) {
        ushort4 ob;
        ob.x = f2bf(fmaxf(o.x, 0.f));
        ob.y = f2bf(fmaxf(o.y, 0.f));
        ob.z = f2bf(fmaxf(o.z, 0.f));
        ob.w = f2bf(fmaxf(o.w, 0.f));
        *(ushort4*)(Yb + (size_t)node * D + d0) = ob;
    } else {
        *(float4*)(Yf + (size_t)node * D + d0) = o;
    }
}

// ---------------------------------------------------------------------------
extern "C" void kernel_launch(void* const* d_in, const int* in_sizes, int n_in,
                              void* d_out, int out_size, void* d_ws, size_t ws_size,
                              hipStream_t stream) {
    const int*   x        = (const int*)d_in[0];
    const int*   z        = (const int*)d_in[1];
    const int*   ei       = (const int*)d_in[2];
    const int*   ea       = (const int*)d_in[3];
    const float* atom_emb = (const float*)d_in[4];
    const float* z_emb    = (const float*)d_in[5];
    const float* bond_emb = (const float*)d_in[6];
    const float* eps      = (const float*)d_in[7];
    const float* W1       = (const float*)d_in[8];
    const float* b1       = (const float*)d_in[9];
    const float* g1       = (const float*)d_in[10];
    const float* be1      = (const float*)d_in[11];
    const float* W2       = (const float*)d_in[12];
    const float* b2       = (const float*)d_in[13];
    const float* bng      = (const float*)d_in[14];
    const float* bnb      = (const float*)d_in[15];

    const int N = in_sizes[1];
    const int E = in_sizes[3] / 3;

    float* h = (float*)d_out;  // final [N,128] fp32

    char* ws = (char*)d_ws;
    size_t off = 0;
    auto alloc = [&](size_t bytes) { void* p = ws + off; off += (bytes + 255) & ~(size_t)255; return p; };
    unsigned short* pre_bf = (unsigned short*)alloc((size_t)N * D * 2);      // 25.6 MB
    unsigned short* extra  = (unsigned short*)alloc((size_t)N * D * 2);      // 25.6 MB (out2 tail)
    (void)extra;
    float* out2 = (float*)pre_bf;                                            // spans pre_bf+extra (51.2 MB)
    unsigned short* out1_bf = (unsigned short*)alloc((size_t)N * 2 * D * 2); // 51.2 MB
    unsigned short* hb      = (unsigned short*)alloc((size_t)N * D * 2);     // 25.6 MB
    int* offsets = (int*)alloc((size_t)(N + 1) * 4);
    int* bucket  = (int*)alloc((size_t)E * 4);
    float* stats = (float*)alloc(1536 * 4);
    unsigned short* w1p  = (unsigned short*)alloc((size_t)2 * D * 2 * D * 2);   // 2 layers, 128x256
    unsigned short* w2p  = (unsigned short*)alloc((size_t)2 * 2 * D * D * 2);   // 2 layers, 256x128
    unsigned short* comb = (unsigned short*)alloc((size_t)2 * 216 * D * 2);
    // transient: counts/cursor alias out1_bf (dead until first GEMM1 write)
    int* counts = (int*)out1_bf;
    int* cursor = counts + N;

    float* sum1 = stats;            // 256
    float* ss1  = stats + 256;      // 256
    float* sum2 = stats + 512;      // 128
    float* ss2  = stats + 640;      // 128
    float* scale1 = stats + 768;    // 256
    float* shift1 = stats + 1024;   // 256
    float* scale2 = stats + 1280;   // 128
    float* shift2 = stats + 1408;   // 128

    const float invN = 1.0f / (float)N;

    // --- CSR build (layer-invariant) + one-time precomputes ---
    hipMemsetAsync(counts, 0, (size_t)N * 2 * sizeof(int), stream);
    histogram_kernel<<<(E + 255) / 256, 256, 0, stream>>>(ei, counts, E);
    scan_kernel<<<1, 1024, 0, stream>>>(counts, offsets, N);
    fill_kernel<<<(E + 255) / 256, 256, 0, stream>>>(ei, ea, offsets, cursor, bucket, E);

    node_init_kernel<<<(N * 32 + 255) / 256, 256, 0, stream>>>(x, z, atom_emb, z_emb, hb, N);
    comb_kernel<<<dim3((216 * D + 255) / 256, 2), 256, 0, stream>>>(bond_emb, comb);
    pack_w_kernel<<<dim3((D * 2 * D + 255) / 256, 2), 256, 0, stream>>>(W1, w1p, D * 2 * D, 8);
    pack_w_kernel<<<dim3((2 * D * D + 255) / 256, 2), 256, 0, stream>>>(W2, w2p, 2 * D * D, 7);

    for (int l = 0; l < 2; ++l) {
        gather_reduce_kernel<<<(N * 16 + 255) / 256, 256, 0, stream>>>(
            offsets, bucket, comb + (size_t)l * 216 * D, hb, eps + l, pre_bf, N);

        hipMemsetAsync(stats, 0, 768 * sizeof(float), stream);

        mfma_gemm_kernel<128, 256, 0, 1><<<(N + 63) / 64, 256, 0, stream>>>(
            pre_bf, w1p + (size_t)l * D * 2 * D, b1 + (size_t)l * 2 * D,
            nullptr, nullptr, out1_bf, nullptr, N);
        colreduce_bf_kernel<<<(N + 127) / 128, 256, 0, stream>>>(out1_bf, N, sum1, ss1, 128);
        finalize_stats_kernel<<<1, 256, 0, stream>>>(sum1, ss1, g1 + (size_t)l * 2 * D,
                                                     be1 + (size_t)l * 2 * D, scale1, shift1,
                                                     256, invN);

        mfma_gemm_kernel<256, 128, 1, 0><<<(N + 63) / 64, 256, 0, stream>>>(
            out1_bf, w2p + (size_t)l * 2 * D * D, b2 + (size_t)l * D,
            scale1, shift1, nullptr, out2, N);
        colreduce_f32_kernel<<<(N + 127) / 128, 256, 0, stream>>>(out2, N, 128, 7, sum2, ss2, 128);
        finalize_stats_kernel<<<1, 128, 0, stream>>>(sum2, ss2, bng + (size_t)l * D,
                                                     bnb + (size_t)l * D, scale2, shift2,
                                                     128, invN);

        bn_apply_kernel<<<(N * 32 + 255) / 256, 256, 0, stream>>>(out2, h, hb, scale2, shift2,
                                                                  N, l == 0 ? 0 : 1);
    }
}

// Round 4
// 806.811 us; speedup vs baseline: 7.9363x; 1.2023x over previous
//
#include <hip/hip_runtime.h>

#define D 128
#define BN_EPS 1e-5f

typedef __attribute__((ext_vector_type(8))) short short8;   // 8 x bf16 (4 VGPRs)
typedef __attribute__((ext_vector_type(4))) float floatx4;  // MFMA accumulator

__device__ __forceinline__ float bf2f(unsigned short u) {
    unsigned int x = ((unsigned int)u) << 16;
    return __builtin_bit_cast(float, x);
}
__device__ __forceinline__ unsigned short f2bf(float f) {
    unsigned int x = __builtin_bit_cast(unsigned int, f);
    x = x + 0x7FFFu + ((x >> 16) & 1u);  // round-to-nearest-even
    return (unsigned short)(x >> 16);
}

// ---------------------------------------------------------------------------
// hb0 = bf16( sum_f atom_emb[f, x[n,f], :] + z_emb[z[n], :] )
__global__ void node_init_kernel(const int* __restrict__ x, const int* __restrict__ z,
                                 const float* __restrict__ atom_emb,
                                 const float* __restrict__ z_emb,
                                 unsigned short* __restrict__ hb, int N) {
    int gid = blockIdx.x * blockDim.x + threadIdx.x;
    int node = gid >> 5;
    if (node >= N) return;
    int d0 = (gid & 31) * 4;
    float4 acc = *(const float4*)(z_emb + (size_t)z[node] * D + d0);
#pragma unroll
    for (int f = 0; f < 9; ++f) {
        int v = x[node * 9 + f];
        const float4 t = *(const float4*)(atom_emb + (size_t)(f * 119 + v) * D + d0);
        acc.x += t.x; acc.y += t.y; acc.z += t.z; acc.w += t.w;
    }
    ushort4 o;
    o.x = f2bf(acc.x); o.y = f2bf(acc.y); o.z = f2bf(acc.z); o.w = f2bf(acc.w);
    *(ushort4*)(hb + (size_t)node * D + d0) = o;
}

// ---------------------------------------------------------------------------
// payload[e] = src | comb_idx<<17  (sequential read+write; comb_idx=(a0*6+a1)*6+a2)
__global__ void payload_kernel(const int* __restrict__ ei, const int* __restrict__ ea,
                               int* __restrict__ payload, int E) {
    int e = blockIdx.x * 256 + threadIdx.x;
    if (e >= E) return;
    int c = (ea[3 * e] * 6 + ea[3 * e + 1]) * 6 + ea[3 * e + 2];
    payload[e] = ei[e] | (c << 17);
}

// ---------------------------------------------------------------------------
// XCD-sliced in-degree histogram: block (blockIdx&7) owns dst slice; counts
// lines stay resident in one XCD's L2. Correct for any blockIdx->XCD mapping.
__global__ void hist_sliced_kernel(const int* __restrict__ ei, int* __restrict__ counts,
                                   int E, int N, int stride) {
    const int slice = blockIdx.x & 7;
    const int group = blockIdx.x >> 3;
    const int lo = (int)((long long)slice * N / 8);
    const int hi = (int)((long long)(slice + 1) * N / 8);
    for (int e = group * 256 + threadIdx.x; e < E; e += stride) {
        int dst = ei[E + e];
        if (dst >= lo && dst < hi) atomicAdd(&counts[dst], 1);
    }
}

// ---------------------------------------------------------------------------
// Parallel exclusive scan of counts[N] -> offsets[N+1], 3 phases.
__global__ void scan_p1_kernel(const int* __restrict__ counts, int* __restrict__ partials, int N) {
    const int tid = threadIdx.x;
    const int base = blockIdx.x * 1024 + tid * 4;
    int4 c = {0, 0, 0, 0};
    if (base + 3 < N) c = *(const int4*)(counts + base);
    else {
        if (base + 0 < N) c.x = counts[base + 0];
        if (base + 1 < N) c.y = counts[base + 1];
        if (base + 2 < N) c.z = counts[base + 2];
        if (base + 3 < N) c.w = counts[base + 3];
    }
    int s = c.x + c.y + c.z + c.w;
#pragma unroll
    for (int off = 32; off > 0; off >>= 1) s += __shfl_xor(s, off, 64);
    __shared__ int ws[4];
    if ((tid & 63) == 0) ws[tid >> 6] = s;
    __syncthreads();
    if (tid == 0) partials[blockIdx.x] = ws[0] + ws[1] + ws[2] + ws[3];
}

__global__ void scan_p2_kernel(int* __restrict__ partials, int nb) {
    const int tid = threadIdx.x;  // 128 threads, nb <= 128
    const int lane = tid & 63, wid = tid >> 6;
    int v = (tid < nb) ? partials[tid] : 0;
    int s = v;
#pragma unroll
    for (int off = 1; off < 64; off <<= 1) {
        int t = __shfl_up(s, off, 64);
        if (lane >= off) s += t;
    }
    __shared__ int ws2[2];
    if (lane == 63) ws2[wid] = s;
    __syncthreads();
    if (wid == 1) s += ws2[0];
    if (tid < nb) partials[tid] = s - v;  // exclusive
}

__global__ void scan_p3_kernel(const int* __restrict__ counts, const int* __restrict__ partials,
                               int* __restrict__ offsets, int N) {
    const int tid = threadIdx.x;
    const int lane = tid & 63, wid = tid >> 6;
    const int base = blockIdx.x * 1024 + tid * 4;
    int4 c = {0, 0, 0, 0};
    if (base + 3 < N) c = *(const int4*)(counts + base);
    else {
        if (base + 0 < N) c.x = counts[base + 0];
        if (base + 1 < N) c.y = counts[base + 1];
        if (base + 2 < N) c.z = counts[base + 2];
        if (base + 3 < N) c.w = counts[base + 3];
    }
    int p1 = c.x, p2 = p1 + c.y, p3 = p2 + c.z, p4 = p3 + c.w;
    int s = p4;
#pragma unroll
    for (int off = 1; off < 64; off <<= 1) {
        int t = __shfl_up(s, off, 64);
        if (lane >= off) s += t;
    }
    __shared__ int ws[4];
    if (lane == 63) ws[wid] = s;
    __syncthreads();
    int wbase = 0;
#pragma unroll
    for (int w = 0; w < 4; ++w) wbase += (w < wid) ? ws[w] : 0;
    int excl = partials[blockIdx.x] + wbase + (s - p4);
    if (base + 0 < N) offsets[base + 1] = excl + p1;
    if (base + 1 < N) offsets[base + 2] = excl + p2;
    if (base + 2 < N) offsets[base + 3] = excl + p3;
    if (base + 3 < N) offsets[base + 4] = excl + p4;
    if (blockIdx.x == 0 && tid == 0) offsets[0] = 0;
}

// ---------------------------------------------------------------------------
// XCD-sliced bucket fill: each slice's bucket region (~800 KB) stays resident
// in one XCD's L2 so the 16 x 4B writes per line merge before writeback.
__global__ void fill_sliced_kernel(const int* __restrict__ ei, const int* __restrict__ payload,
                                   const int* __restrict__ offsets, int* __restrict__ cursor,
                                   int* __restrict__ bucket, int E, int N, int stride) {
    const int slice = blockIdx.x & 7;
    const int group = blockIdx.x >> 3;
    const int lo = (int)((long long)slice * N / 8);
    const int hi = (int)((long long)(slice + 1) * N / 8);
    for (int e = group * 256 + threadIdx.x; e < E; e += stride) {
        int dst = ei[E + e];
        if (dst >= lo && dst < hi) {
            int pos = offsets[dst] + atomicAdd(&cursor[dst], 1);
            bucket[pos] = payload[e];
        }
    }
}

// ---------------------------------------------------------------------------
// comb[layer][c][d] = bf16( b0[a0][d] + b1[a1][d] + b2[a2][d] )
__global__ void comb_kernel(const float* __restrict__ bond_emb, unsigned short* __restrict__ comb) {
    int idx = blockIdx.x * 256 + threadIdx.x;  // c*128 + d
    if (idx >= 216 * D) return;
    int c = idx >> 7, d = idx & 127;
    int a0 = c / 36, a1 = (c / 6) % 6, a2 = c % 6;
    const float* b = bond_emb + (size_t)blockIdx.y * 3 * 6 * D;
    float v = b[(0 * 6 + a0) * D + d] + b[(1 * 6 + a1) * D + d] + b[(2 * 6 + a2) * D + d];
    comb[(size_t)blockIdx.y * 216 * D + idx] = f2bf(v);
}

// ---------------------------------------------------------------------------
// Pack W [K][NCOLS] fp32 row-major -> Wp[k/32][n][k%32] bf16 (MFMA B-fragment order).
__global__ void pack_w_kernel(const float* __restrict__ W, unsigned short* __restrict__ Wp,
                              int total, int logN) {
    int idx = blockIdx.x * 256 + threadIdx.x;
    if (idx >= total) return;
    int NCOLS = 1 << logN;
    int k = idx >> logN, n = idx & (NCOLS - 1);
    const float* Wl = W + (size_t)blockIdx.y * total;
    unsigned short* Wpl = Wp + (size_t)blockIdx.y * total;
    Wpl[((size_t)(k >> 5) * NCOLS + n) * 32 + (k & 31)] = f2bf(Wl[idx]);
}

// ---------------------------------------------------------------------------
// pre[n] = bf16( (1+eps)*h[n] + sum_{e in in(n)} relu(h[src_e] + comb[c_e]) )
// 16 lanes per node, 8 bf16/lane; 4-wide unrolled (8 independent loads in flight).
__global__ __launch_bounds__(256)
void gather_reduce_kernel(const int* __restrict__ offsets, const int* __restrict__ bucket,
                          const unsigned short* __restrict__ comb,
                          const unsigned short* __restrict__ hb,
                          const float* __restrict__ eps_l,
                          unsigned short* __restrict__ pre, int N) {
    int gid = blockIdx.x * blockDim.x + threadIdx.x;
    int node = gid >> 4;
    if (node >= N) return;
    int d0 = (gid & 15) * 8;

    union U8 { int4 i; unsigned short u[8]; };
    float s = 1.0f + eps_l[0];
    float a[8];
    {
        U8 hv; hv.i = *(const int4*)(hb + (size_t)node * D + d0);
#pragma unroll
        for (int j = 0; j < 8; ++j) a[j] = bf2f(hv.u[j]) * s;
    }
    const int beg = offsets[node], end = offsets[node + 1];
    for (int p = beg; p < end; p += 4) {
        int rem = end - p;
        int pk0 = bucket[p];
        int pk1 = bucket[rem > 1 ? p + 1 : p];
        int pk2 = bucket[rem > 2 ? p + 2 : p];
        int pk3 = bucket[rem > 3 ? p + 3 : p];
        U8 h0, h1, h2, h3, c0, c1, c2, c3;
        h0.i = *(const int4*)(hb + (size_t)(pk0 & 0x1FFFF) * D + d0);
        c0.i = *(const int4*)(comb + (size_t)((pk0 >> 17) & 0xFF) * D + d0);
        h1.i = *(const int4*)(hb + (size_t)(pk1 & 0x1FFFF) * D + d0);
        c1.i = *(const int4*)(comb + (size_t)((pk1 >> 17) & 0xFF) * D + d0);
        h2.i = *(const int4*)(hb + (size_t)(pk2 & 0x1FFFF) * D + d0);
        c2.i = *(const int4*)(comb + (size_t)((pk2 >> 17) & 0xFF) * D + d0);
        h3.i = *(const int4*)(hb + (size_t)(pk3 & 0x1FFFF) * D + d0);
        c3.i = *(const int4*)(comb + (size_t)((pk3 >> 17) & 0xFF) * D + d0);
#pragma unroll
        for (int j = 0; j < 8; ++j) a[j] += fmaxf(bf2f(h0.u[j]) + bf2f(c0.u[j]), 0.0f);
        if (rem > 1) {
#pragma unroll
            for (int j = 0; j < 8; ++j) a[j] += fmaxf(bf2f(h1.u[j]) + bf2f(c1.u[j]), 0.0f);
        }
        if (rem > 2) {
#pragma unroll
            for (int j = 0; j < 8; ++j) a[j] += fmaxf(bf2f(h2.u[j]) + bf2f(c2.u[j]), 0.0f);
        }
        if (rem > 3) {
#pragma unroll
            for (int j = 0; j < 8; ++j) a[j] += fmaxf(bf2f(h3.u[j]) + bf2f(c3.u[j]), 0.0f);
        }
    }
    U8 o;
#pragma unroll
    for (int j = 0; j < 8; ++j) o.u[j] = f2bf(a[j]);
    *(int4*)(pre + (size_t)node * D + d0) = o.i;
}

// ---------------------------------------------------------------------------
// MFMA GEMM with fused per-column sum/sum-sq (from fp32 accumulators).
// C[M,NCOLS] = A'[M,K] @ W[K,NCOLS] + bias; TRANSFORM: A' = bf16(relu(A*sc+sh)).
template <int K, int NCOLS, int TRANSFORM, int OUTBF>
__global__ __launch_bounds__(256)
void mfma_gemm_kernel(const unsigned short* __restrict__ A,
                      const unsigned short* __restrict__ Wp,
                      const float* __restrict__ bias,
                      const float* __restrict__ tscale, const float* __restrict__ tshift,
                      unsigned short* __restrict__ Cbf, float* __restrict__ Cf,
                      float* __restrict__ sumO, float* __restrict__ ssO, int M) {
    constexpr int NT = NCOLS / 16;
    __shared__ float red[NCOLS * 2];
    const int tid = threadIdx.x;
    for (int i = tid; i < NCOLS * 2; i += 256) red[i] = 0.f;

    const int wave = tid >> 6, lane = tid & 63;
    const int quad = lane >> 4, ln = lane & 15;
    const int m_base = blockIdx.x * 64 + wave * 16;
    int arow = m_base + ln;
    if (arow >= M) arow = M - 1;
    const int kq = quad * 8;

    floatx4 acc[NT];
#pragma unroll
    for (int t = 0; t < NT; ++t) acc[t] = (floatx4){0.f, 0.f, 0.f, 0.f};

#pragma unroll
    for (int k0 = 0; k0 < K; k0 += 32) {
        short8 afrag;
        if constexpr (TRANSFORM) {
            union { int4 i; unsigned short u[8]; } raw;
            raw.i = *(const int4*)(A + (size_t)arow * K + k0 + kq);
            float4 sc0 = *(const float4*)(tscale + k0 + kq);
            float4 sc1 = *(const float4*)(tscale + k0 + kq + 4);
            float4 sh0 = *(const float4*)(tshift + k0 + kq);
            float4 sh1 = *(const float4*)(tshift + k0 + kq + 4);
            union { short8 v; unsigned short u[8]; } au;
            au.u[0] = f2bf(fmaxf(bf2f(raw.u[0]) * sc0.x + sh0.x, 0.f));
            au.u[1] = f2bf(fmaxf(bf2f(raw.u[1]) * sc0.y + sh0.y, 0.f));
            au.u[2] = f2bf(fmaxf(bf2f(raw.u[2]) * sc0.z + sh0.z, 0.f));
            au.u[3] = f2bf(fmaxf(bf2f(raw.u[3]) * sc0.w + sh0.w, 0.f));
            au.u[4] = f2bf(fmaxf(bf2f(raw.u[4]) * sc1.x + sh1.x, 0.f));
            au.u[5] = f2bf(fmaxf(bf2f(raw.u[5]) * sc1.y + sh1.y, 0.f));
            au.u[6] = f2bf(fmaxf(bf2f(raw.u[6]) * sc1.z + sh1.z, 0.f));
            au.u[7] = f2bf(fmaxf(bf2f(raw.u[7]) * sc1.w + sh1.w, 0.f));
            afrag = au.v;
        } else {
            afrag = *(const short8*)(A + (size_t)arow * K + k0 + kq);
        }
#pragma unroll
        for (int t = 0; t < NT; ++t) {
            short8 bfrag = *(const short8*)(Wp + ((size_t)(k0 >> 5) * NCOLS + (t * 16 + ln)) * 32 + kq);
            acc[t] = __builtin_amdgcn_mfma_f32_16x16x32_bf16(afrag, bfrag, acc[t], 0, 0, 0);
        }
    }

    __syncthreads();  // red[] zero-init visible
#pragma unroll
    for (int t = 0; t < NT; ++t) {
        int col = t * 16 + ln;
        float bv = bias[col];
        float sv = 0.f, qv = 0.f;
#pragma unroll
        for (int r = 0; r < 4; ++r) {
            int row = m_base + quad * 4 + r;
            if (row < M) {
                float v = acc[t][r] + bv;
                sv += v; qv += v * v;
                if constexpr (OUTBF) Cbf[(size_t)row * NCOLS + col] = f2bf(v);
                else                 Cf[(size_t)row * NCOLS + col] = v;
            }
        }
        // reduce over the 4 quads (lanes ln, ln+16, ln+32, ln+48 share col)
        sv += __shfl_xor(sv, 16, 64); sv += __shfl_xor(sv, 32, 64);
        qv += __shfl_xor(qv, 16, 64); qv += __shfl_xor(qv, 32, 64);
        if (quad == 0) {
            atomicAdd(&red[col], sv);
            atomicAdd(&red[NCOLS + col], qv);
        }
    }
    __syncthreads();
    for (int i = tid; i < NCOLS; i += 256) {
        atomicAdd(&sumO[i], red[i]);
        atomicAdd(&ssO[i], red[NCOLS + i]);
    }
}

// ---------------------------------------------------------------------------
__global__ void finalize_stats_kernel(const float* __restrict__ sum, const float* __restrict__ ss,
                                      const float* __restrict__ g, const float* __restrict__ b,
                                      float* __restrict__ scale, float* __restrict__ shift,
                                      int C, float invN) {
    int j = blockIdx.x * blockDim.x + threadIdx.x;
    if (j >= C) return;
    float mean = sum[j] * invN;
    float var = ss[j] * invN - mean * mean;
    float inv = 1.0f / sqrtf(var + BN_EPS);
    float sc = g[j] * inv;
    scale[j] = sc;
    shift[j] = b[j] - mean * sc;
}

// ---------------------------------------------------------------------------
// mode 0: hb = bf16(relu(bn(out2)))   mode 1: h = bn(out2) fp32 (final)
__global__ void bn_apply_kernel(const float* __restrict__ X, float* __restrict__ Yf,
                                unsigned short* __restrict__ Yb,
                                const float* __restrict__ scale, const float* __restrict__ shift,
                                int N, int mode) {
    int gid = blockIdx.x * blockDim.x + threadIdx.x;
    int node = gid >> 5;
    if (node >= N) return;
    int d0 = (gid & 31) * 4;
    float4 v = *(const float4*)(X + (size_t)node * D + d0);
    float4 sc = *(const float4*)(scale + d0);
    float4 sh = *(const float4*)(shift + d0);
    float4 o;
    o.x = v.x * sc.x + sh.x;
    o.y = v.y * sc.y + sh.y;
    o.z = v.z * sc.z + sh.z;
    o.w = v.w * sc.w + sh.w;
    if (mode == 0) {
        ushort4 ob;
        ob.x = f2bf(fmaxf(o.x, 0.f));
        ob.y = f2bf(fmaxf(o.y, 0.f));
        ob.z = f2bf(fmaxf(o.z, 0.f));
        ob.w = f2bf(fmaxf(o.w, 0.f));
        *(ushort4*)(Yb + (size_t)node * D + d0) = ob;
    } else {
        *(float4*)(Yf + (size_t)node * D + d0) = o;
    }
}

// ---------------------------------------------------------------------------
extern "C" void kernel_launch(void* const* d_in, const int* in_sizes, int n_in,
                              void* d_out, int out_size, void* d_ws, size_t ws_size,
                              hipStream_t stream) {
    const int*   x        = (const int*)d_in[0];
    const int*   z        = (const int*)d_in[1];
    const int*   ei       = (const int*)d_in[2];
    const int*   ea       = (const int*)d_in[3];
    const float* atom_emb = (const float*)d_in[4];
    const float* z_emb    = (const float*)d_in[5];
    const float* bond_emb = (const float*)d_in[6];
    const float* eps      = (const float*)d_in[7];
    const float* W1       = (const float*)d_in[8];
    const float* b1       = (const float*)d_in[9];
    const float* g1       = (const float*)d_in[10];
    const float* be1      = (const float*)d_in[11];
    const float* W2       = (const float*)d_in[12];
    const float* b2       = (const float*)d_in[13];
    const float* bng      = (const float*)d_in[14];
    const float* bnb      = (const float*)d_in[15];

    const int N = in_sizes[1];
    const int E = in_sizes[3] / 3;

    float* h = (float*)d_out;  // final [N,128] fp32

    char* ws = (char*)d_ws;
    size_t off = 0;
    auto alloc = [&](size_t bytes) { void* p = ws + off; off += (bytes + 255) & ~(size_t)255; return p; };
    unsigned short* pre_bf = (unsigned short*)alloc((size_t)N * D * 2);      // 25.6 MB
    unsigned short* extra  = (unsigned short*)alloc((size_t)N * D * 2);      // 25.6 MB (out2 tail)
    (void)extra;
    float* out2 = (float*)pre_bf;                                            // spans pre_bf+extra
    unsigned short* out1_bf = (unsigned short*)alloc((size_t)N * 2 * D * 2); // 51.2 MB
    unsigned short* hb      = (unsigned short*)alloc((size_t)N * D * 2);     // 25.6 MB
    int* offsets = (int*)alloc((size_t)(N + 1) * 4);
    int* bucket  = (int*)alloc((size_t)E * 4);
    int* payload = (int*)alloc((size_t)E * 4);
    float* stats = (float*)alloc(1536 * 4);
    int* partials = (int*)alloc(128 * 4);
    unsigned short* w1p  = (unsigned short*)alloc((size_t)2 * D * 2 * D * 2);
    unsigned short* w2p  = (unsigned short*)alloc((size_t)2 * 2 * D * D * 2);
    unsigned short* comb = (unsigned short*)alloc((size_t)2 * 216 * D * 2);
    // transient: counts/cursor alias out1_bf (dead until first GEMM1 write)
    int* counts = (int*)out1_bf;
    int* cursor = counts + N;

    float* sum1 = stats;            // 256
    float* ss1  = stats + 256;      // 256
    float* sum2 = stats + 512;      // 128
    float* ss2  = stats + 640;      // 128
    float* scale1 = stats + 768;    // 256
    float* shift1 = stats + 1024;   // 256
    float* scale2 = stats + 1280;   // 128
    float* shift2 = stats + 1408;   // 128

    const float invN = 1.0f / (float)N;
    const int nb = (N + 1023) / 1024;
    const int SLICED_BLOCKS = 512;            // 64 groups x 8 slices
    const int SLICED_STRIDE = 64 * 256;

    // --- CSR build (layer-invariant) + one-time precomputes ---
    hipMemsetAsync(counts, 0, (size_t)N * 2 * sizeof(int), stream);
    payload_kernel<<<(E + 255) / 256, 256, 0, stream>>>(ei, ea, payload, E);
    hist_sliced_kernel<<<SLICED_BLOCKS, 256, 0, stream>>>(ei, counts, E, N, SLICED_STRIDE);
    scan_p1_kernel<<<nb, 256, 0, stream>>>(counts, partials, N);
    scan_p2_kernel<<<1, 128, 0, stream>>>(partials, nb);
    scan_p3_kernel<<<nb, 256, 0, stream>>>(counts, partials, offsets, N);
    fill_sliced_kernel<<<SLICED_BLOCKS, 256, 0, stream>>>(ei, payload, offsets, cursor, bucket,
                                                          E, N, SLICED_STRIDE);

    node_init_kernel<<<(N * 32 + 255) / 256, 256, 0, stream>>>(x, z, atom_emb, z_emb, hb, N);
    comb_kernel<<<dim3((216 * D + 255) / 256, 2), 256, 0, stream>>>(bond_emb, comb);
    pack_w_kernel<<<dim3((D * 2 * D + 255) / 256, 2), 256, 0, stream>>>(W1, w1p, D * 2 * D, 8);
    pack_w_kernel<<<dim3((2 * D * D + 255) / 256, 2), 256, 0, stream>>>(W2, w2p, 2 * D * D, 7);

    for (int l = 0; l < 2; ++l) {
        gather_reduce_kernel<<<(N * 16 + 255) / 256, 256, 0, stream>>>(
            offsets, bucket, comb + (size_t)l * 216 * D, hb, eps + l, pre_bf, N);

        hipMemsetAsync(stats, 0, 768 * sizeof(float), stream);

        mfma_gemm_kernel<128, 256, 0, 1><<<(N + 63) / 64, 256, 0, stream>>>(
            pre_bf, w1p + (size_t)l * D * 2 * D, b1 + (size_t)l * 2 * D,
            nullptr, nullptr, out1_bf, nullptr, sum1, ss1, N);
        finalize_stats_kernel<<<1, 256, 0, stream>>>(sum1, ss1, g1 + (size_t)l * 2 * D,
                                                     be1 + (size_t)l * 2 * D, scale1, shift1,
                                                     256, invN);

        mfma_gemm_kernel<256, 128, 1, 0><<<(N + 63) / 64, 256, 0, stream>>>(
            out1_bf, w2p + (size_t)l * 2 * D * D, b2 + (size_t)l * D,
            scale1, shift1, nullptr, out2, sum2, ss2, N);
        finalize_stats_kernel<<<1, 128, 0, stream>>>(sum2, ss2, bng + (size_t)l * D,
                                                     bnb + (size_t)l * D, scale2, shift2,
                                                     128, invN);

        bn_apply_kernel<<<(N * 32 + 255) / 256, 256, 0, stream>>>(out2, h, hb, scale2, shift2,
                                                                  N, l == 0 ? 0 : 1);
    }
}

// Round 5
// 733.108 us; speedup vs baseline: 8.7342x; 1.1005x over previous
//
#include <hip/hip_runtime.h>

#define D 128
#define BN_EPS 1e-5f

typedef __attribute__((ext_vector_type(8))) short short8;   // 8 x bf16 (4 VGPRs)
typedef __attribute__((ext_vector_type(4))) float floatx4;  // MFMA accumulator

__device__ __forceinline__ float bf2f(unsigned short u) {
    unsigned int x = ((unsigned int)u) << 16;
    return __builtin_bit_cast(float, x);
}
__device__ __forceinline__ unsigned short f2bf(float f) {
    unsigned int x = __builtin_bit_cast(unsigned int, f);
    x = x + 0x7FFFu + ((x >> 16) & 1u);  // round-to-nearest-even
    return (unsigned short)(x >> 16);
}

// ---------------------------------------------------------------------------
// hb0 = bf16( sum_f atom_emb[f, x[n,f], :] + z_emb[z[n], :] )
__global__ void node_init_kernel(const int* __restrict__ x, const int* __restrict__ z,
                                 const float* __restrict__ atom_emb,
                                 const float* __restrict__ z_emb,
                                 unsigned short* __restrict__ hb, int N) {
    int gid = blockIdx.x * blockDim.x + threadIdx.x;
    int node = gid >> 5;
    if (node >= N) return;
    int d0 = (gid & 31) * 4;
    float4 acc = *(const float4*)(z_emb + (size_t)z[node] * D + d0);
#pragma unroll
    for (int f = 0; f < 9; ++f) {
        int v = x[node * 9 + f];
        const float4 t = *(const float4*)(atom_emb + (size_t)(f * 119 + v) * D + d0);
        acc.x += t.x; acc.y += t.y; acc.z += t.z; acc.w += t.w;
    }
    ushort4 o;
    o.x = f2bf(acc.x); o.y = f2bf(acc.y); o.z = f2bf(acc.z); o.w = f2bf(acc.w);
    *(ushort4*)(hb + (size_t)node * D + d0) = o;
}

// ---------------------------------------------------------------------------
// payload[e] = src | comb_idx<<17
__global__ void payload_kernel(const int* __restrict__ ei, const int* __restrict__ ea,
                               int* __restrict__ payload, int E) {
    int e = blockIdx.x * 256 + threadIdx.x;
    if (e >= E) return;
    int c = (ea[3 * e] * 6 + ea[3 * e + 1]) * 6 + ea[3 * e + 2];
    payload[e] = ei[e] | (c << 17);
}

// ---------------------------------------------------------------------------
// XCD-sliced in-degree histogram.
__global__ void hist_sliced_kernel(const int* __restrict__ ei, int* __restrict__ counts,
                                   int E, int N, int stride) {
    const int slice = blockIdx.x & 7;
    const int group = blockIdx.x >> 3;
    const int lo = (int)((long long)slice * N / 8);
    const int hi = (int)((long long)(slice + 1) * N / 8);
    for (int e = group * 256 + threadIdx.x; e < E; e += stride) {
        int dst = ei[E + e];
        if (dst >= lo && dst < hi) atomicAdd(&counts[dst], 1);
    }
}

// ---------------------------------------------------------------------------
// Parallel exclusive scan of counts[N] -> offsets[N+1], 3 phases.
__global__ void scan_p1_kernel(const int* __restrict__ counts, int* __restrict__ partials, int N) {
    const int tid = threadIdx.x;
    const int base = blockIdx.x * 1024 + tid * 4;
    int4 c = {0, 0, 0, 0};
    if (base + 3 < N) c = *(const int4*)(counts + base);
    else {
        if (base + 0 < N) c.x = counts[base + 0];
        if (base + 1 < N) c.y = counts[base + 1];
        if (base + 2 < N) c.z = counts[base + 2];
        if (base + 3 < N) c.w = counts[base + 3];
    }
    int s = c.x + c.y + c.z + c.w;
#pragma unroll
    for (int off = 32; off > 0; off >>= 1) s += __shfl_xor(s, off, 64);
    __shared__ int ws[4];
    if ((tid & 63) == 0) ws[tid >> 6] = s;
    __syncthreads();
    if (tid == 0) partials[blockIdx.x] = ws[0] + ws[1] + ws[2] + ws[3];
}

__global__ void scan_p2_kernel(int* __restrict__ partials, int nb) {
    const int tid = threadIdx.x;  // 128 threads, nb <= 128
    const int lane = tid & 63, wid = tid >> 6;
    int v = (tid < nb) ? partials[tid] : 0;
    int s = v;
#pragma unroll
    for (int off = 1; off < 64; off <<= 1) {
        int t = __shfl_up(s, off, 64);
        if (lane >= off) s += t;
    }
    __shared__ int ws2[2];
    if (lane == 63) ws2[wid] = s;
    __syncthreads();
    if (wid == 1) s += ws2[0];
    if (tid < nb) partials[tid] = s - v;  // exclusive
}

__global__ void scan_p3_kernel(const int* __restrict__ counts, const int* __restrict__ partials,
                               int* __restrict__ offsets, int N) {
    const int tid = threadIdx.x;
    const int lane = tid & 63, wid = tid >> 6;
    const int base = blockIdx.x * 1024 + tid * 4;
    int4 c = {0, 0, 0, 0};
    if (base + 3 < N) c = *(const int4*)(counts + base);
    else {
        if (base + 0 < N) c.x = counts[base + 0];
        if (base + 1 < N) c.y = counts[base + 1];
        if (base + 2 < N) c.z = counts[base + 2];
        if (base + 3 < N) c.w = counts[base + 3];
    }
    int p1 = c.x, p2 = p1 + c.y, p3 = p2 + c.z, p4 = p3 + c.w;
    int s = p4;
#pragma unroll
    for (int off = 1; off < 64; off <<= 1) {
        int t = __shfl_up(s, off, 64);
        if (lane >= off) s += t;
    }
    __shared__ int ws[4];
    if (lane == 63) ws[wid] = s;
    __syncthreads();
    int wbase = 0;
#pragma unroll
    for (int w = 0; w < 4; ++w) wbase += (w < wid) ? ws[w] : 0;
    int excl = partials[blockIdx.x] + wbase + (s - p4);
    if (base + 0 < N) offsets[base + 1] = excl + p1;
    if (base + 1 < N) offsets[base + 2] = excl + p2;
    if (base + 2 < N) offsets[base + 3] = excl + p3;
    if (base + 3 < N) offsets[base + 4] = excl + p4;
    if (blockIdx.x == 0 && tid == 0) offsets[0] = 0;
}

// ---------------------------------------------------------------------------
// XCD-sliced bucket fill.
__global__ void fill_sliced_kernel(const int* __restrict__ ei, const int* __restrict__ payload,
                                   const int* __restrict__ offsets, int* __restrict__ cursor,
                                   int* __restrict__ bucket, int E, int N, int stride) {
    const int slice = blockIdx.x & 7;
    const int group = blockIdx.x >> 3;
    const int lo = (int)((long long)slice * N / 8);
    const int hi = (int)((long long)(slice + 1) * N / 8);
    for (int e = group * 256 + threadIdx.x; e < E; e += stride) {
        int dst = ei[E + e];
        if (dst >= lo && dst < hi) {
            int pos = offsets[dst] + atomicAdd(&cursor[dst], 1);
            bucket[pos] = payload[e];
        }
    }
}

// ---------------------------------------------------------------------------
// comb[layer][c][d] = bf16( b0[a0][d] + b1[a1][d] + b2[a2][d] )
__global__ void comb_kernel(const float* __restrict__ bond_emb, unsigned short* __restrict__ comb) {
    int idx = blockIdx.x * 256 + threadIdx.x;  // c*128 + d
    if (idx >= 216 * D) return;
    int c = idx >> 7, d = idx & 127;
    int a0 = c / 36, a1 = (c / 6) % 6, a2 = c % 6;
    const float* b = bond_emb + (size_t)blockIdx.y * 3 * 6 * D;
    float v = b[(0 * 6 + a0) * D + d] + b[(1 * 6 + a1) * D + d] + b[(2 * 6 + a2) * D + d];
    comb[(size_t)blockIdx.y * 216 * D + idx] = f2bf(v);
}

// ---------------------------------------------------------------------------
// Pack W [K][NCOLS] fp32 row-major -> Wp[k/32][n][k%32] bf16 (MFMA B-fragment order).
__global__ void pack_w_kernel(const float* __restrict__ W, unsigned short* __restrict__ Wp,
                              int total, int logN) {
    int idx = blockIdx.x * 256 + threadIdx.x;
    if (idx >= total) return;
    int NCOLS = 1 << logN;
    int k = idx >> logN, n = idx & (NCOLS - 1);
    const float* Wl = W + (size_t)blockIdx.y * total;
    unsigned short* Wpl = Wp + (size_t)blockIdx.y * total;
    Wpl[((size_t)(k >> 5) * NCOLS + n) * 32 + (k & 31)] = f2bf(Wl[idx]);
}

// ---------------------------------------------------------------------------
// pre[n] = bf16( (1+eps)*h[n] + sum_{e in in(n)} relu(h[src_e] + comb[c_e]) )
__global__ __launch_bounds__(256)
void gather_reduce_kernel(const int* __restrict__ offsets, const int* __restrict__ bucket,
                          const unsigned short* __restrict__ comb,
                          const unsigned short* __restrict__ hb,
                          const float* __restrict__ eps_l,
                          unsigned short* __restrict__ pre, int N) {
    int gid = blockIdx.x * blockDim.x + threadIdx.x;
    int node = gid >> 4;
    if (node >= N) return;
    int d0 = (gid & 15) * 8;

    union U8 { int4 i; unsigned short u[8]; };
    float s = 1.0f + eps_l[0];
    float a[8];
    {
        U8 hv; hv.i = *(const int4*)(hb + (size_t)node * D + d0);
#pragma unroll
        for (int j = 0; j < 8; ++j) a[j] = bf2f(hv.u[j]) * s;
    }
    const int beg = offsets[node], end = offsets[node + 1];
    for (int p = beg; p < end; p += 4) {
        int rem = end - p;
        int pk0 = bucket[p];
        int pk1 = bucket[rem > 1 ? p + 1 : p];
        int pk2 = bucket[rem > 2 ? p + 2 : p];
        int pk3 = bucket[rem > 3 ? p + 3 : p];
        U8 h0, h1, h2, h3, c0, c1, c2, c3;
        h0.i = *(const int4*)(hb + (size_t)(pk0 & 0x1FFFF) * D + d0);
        c0.i = *(const int4*)(comb + (size_t)((pk0 >> 17) & 0xFF) * D + d0);
        h1.i = *(const int4*)(hb + (size_t)(pk1 & 0x1FFFF) * D + d0);
        c1.i = *(const int4*)(comb + (size_t)((pk1 >> 17) & 0xFF) * D + d0);
        h2.i = *(const int4*)(hb + (size_t)(pk2 & 0x1FFFF) * D + d0);
        c2.i = *(const int4*)(comb + (size_t)((pk2 >> 17) & 0xFF) * D + d0);
        h3.i = *(const int4*)(hb + (size_t)(pk3 & 0x1FFFF) * D + d0);
        c3.i = *(const int4*)(comb + (size_t)((pk3 >> 17) & 0xFF) * D + d0);
#pragma unroll
        for (int j = 0; j < 8; ++j) a[j] += fmaxf(bf2f(h0.u[j]) + bf2f(c0.u[j]), 0.0f);
        if (rem > 1) {
#pragma unroll
            for (int j = 0; j < 8; ++j) a[j] += fmaxf(bf2f(h1.u[j]) + bf2f(c1.u[j]), 0.0f);
        }
        if (rem > 2) {
#pragma unroll
            for (int j = 0; j < 8; ++j) a[j] += fmaxf(bf2f(h2.u[j]) + bf2f(c2.u[j]), 0.0f);
        }
        if (rem > 3) {
#pragma unroll
            for (int j = 0; j < 8; ++j) a[j] += fmaxf(bf2f(h3.u[j]) + bf2f(c3.u[j]), 0.0f);
        }
    }
    U8 o;
#pragma unroll
    for (int j = 0; j < 8; ++j) o.u[j] = f2bf(a[j]);
    *(int4*)(pre + (size_t)node * D + d0) = o.i;
}

// ---------------------------------------------------------------------------
// MFMA GEMM with fused per-column sum/sum-sq -> NON-ATOMIC per-block partials.
// partial[blockIdx] = {sum[NCOLS], ss[NCOLS]} (coalesced store; reduced later).
template <int K, int NCOLS, int TRANSFORM, int OUTBF>
__global__ __launch_bounds__(256)
void mfma_gemm_kernel(const unsigned short* __restrict__ A,
                      const unsigned short* __restrict__ Wp,
                      const float* __restrict__ bias,
                      const float* __restrict__ tscale, const float* __restrict__ tshift,
                      unsigned short* __restrict__ Cbf, float* __restrict__ Cf,
                      float* __restrict__ partial, int M) {
    constexpr int NT = NCOLS / 16;
    __shared__ float red[NCOLS * 2];
    const int tid = threadIdx.x;
    for (int i = tid; i < NCOLS * 2; i += 256) red[i] = 0.f;

    const int wave = tid >> 6, lane = tid & 63;
    const int quad = lane >> 4, ln = lane & 15;
    const int m_base = blockIdx.x * 64 + wave * 16;
    int arow = m_base + ln;
    if (arow >= M) arow = M - 1;
    const int kq = quad * 8;

    floatx4 acc[NT];
#pragma unroll
    for (int t = 0; t < NT; ++t) acc[t] = (floatx4){0.f, 0.f, 0.f, 0.f};

#pragma unroll
    for (int k0 = 0; k0 < K; k0 += 32) {
        short8 afrag;
        if constexpr (TRANSFORM) {
            union { int4 i; unsigned short u[8]; } raw;
            raw.i = *(const int4*)(A + (size_t)arow * K + k0 + kq);
            float4 sc0 = *(const float4*)(tscale + k0 + kq);
            float4 sc1 = *(const float4*)(tscale + k0 + kq + 4);
            float4 sh0 = *(const float4*)(tshift + k0 + kq);
            float4 sh1 = *(const float4*)(tshift + k0 + kq + 4);
            union { short8 v; unsigned short u[8]; } au;
            au.u[0] = f2bf(fmaxf(bf2f(raw.u[0]) * sc0.x + sh0.x, 0.f));
            au.u[1] = f2bf(fmaxf(bf2f(raw.u[1]) * sc0.y + sh0.y, 0.f));
            au.u[2] = f2bf(fmaxf(bf2f(raw.u[2]) * sc0.z + sh0.z, 0.f));
            au.u[3] = f2bf(fmaxf(bf2f(raw.u[3]) * sc0.w + sh0.w, 0.f));
            au.u[4] = f2bf(fmaxf(bf2f(raw.u[4]) * sc1.x + sh1.x, 0.f));
            au.u[5] = f2bf(fmaxf(bf2f(raw.u[5]) * sc1.y + sh1.y, 0.f));
            au.u[6] = f2bf(fmaxf(bf2f(raw.u[6]) * sc1.z + sh1.z, 0.f));
            au.u[7] = f2bf(fmaxf(bf2f(raw.u[7]) * sc1.w + sh1.w, 0.f));
            afrag = au.v;
        } else {
            afrag = *(const short8*)(A + (size_t)arow * K + k0 + kq);
        }
#pragma unroll
        for (int t = 0; t < NT; ++t) {
            short8 bfrag = *(const short8*)(Wp + ((size_t)(k0 >> 5) * NCOLS + (t * 16 + ln)) * 32 + kq);
            acc[t] = __builtin_amdgcn_mfma_f32_16x16x32_bf16(afrag, bfrag, acc[t], 0, 0, 0);
        }
    }

    __syncthreads();  // red[] zero-init visible
#pragma unroll
    for (int t = 0; t < NT; ++t) {
        int col = t * 16 + ln;
        float bv = bias[col];
        float sv = 0.f, qv = 0.f;
#pragma unroll
        for (int r = 0; r < 4; ++r) {
            int row = m_base + quad * 4 + r;
            if (row < M) {
                float v = acc[t][r] + bv;
                sv += v; qv += v * v;
                if constexpr (OUTBF) Cbf[(size_t)row * NCOLS + col] = f2bf(v);
                else                 Cf[(size_t)row * NCOLS + col] = v;
            }
        }
        sv += __shfl_xor(sv, 16, 64); sv += __shfl_xor(sv, 32, 64);
        qv += __shfl_xor(qv, 16, 64); qv += __shfl_xor(qv, 32, 64);
        if (quad == 0) {
            atomicAdd(&red[col], sv);          // LDS atomics: 4 waves only, cheap
            atomicAdd(&red[NCOLS + col], qv);
        }
    }
    __syncthreads();
    float* pout = partial + (size_t)blockIdx.x * (NCOLS * 2);
    for (int i = tid; i < NCOLS * 2; i += 256) pout[i] = red[i];  // non-atomic, coalesced
}

// ---------------------------------------------------------------------------
// One block per column: tree-reduce per-block partials, emit scale/shift.
template <int NCOLS>
__global__ __launch_bounds__(256)
void reduce_stats_kernel(const float* __restrict__ partial, int nb,
                         const float* __restrict__ g, const float* __restrict__ b,
                         float* __restrict__ scale, float* __restrict__ shift, float invN) {
    const int col = blockIdx.x;
    const int tid = threadIdx.x;
    float s = 0.f, q = 0.f;
    for (int bb = tid; bb < nb; bb += 256) {
        const float* p = partial + (size_t)bb * (NCOLS * 2);
        s += p[col];
        q += p[NCOLS + col];
    }
#pragma unroll
    for (int off = 32; off > 0; off >>= 1) {
        s += __shfl_xor(s, off, 64);
        q += __shfl_xor(q, off, 64);
    }
    __shared__ float ws[4], wq[4];
    if ((tid & 63) == 0) { ws[tid >> 6] = s; wq[tid >> 6] = q; }
    __syncthreads();
    if (tid == 0) {
        s = ws[0] + ws[1] + ws[2] + ws[3];
        q = wq[0] + wq[1] + wq[2] + wq[3];
        float mean = s * invN;
        float var = q * invN - mean * mean;
        float inv = 1.0f / sqrtf(var + BN_EPS);
        float sc = g[col] * inv;
        scale[col] = sc;
        shift[col] = b[col] - mean * sc;
    }
}

// ---------------------------------------------------------------------------
// mode 0: hb = bf16(relu(bn(out2)))   mode 1: h = bn(out2) fp32 (final)
__global__ void bn_apply_kernel(const float* __restrict__ X, float* __restrict__ Yf,
                                unsigned short* __restrict__ Yb,
                                const float* __restrict__ scale, const float* __restrict__ shift,
                                int N, int mode) {
    int gid = blockIdx.x * blockDim.x + threadIdx.x;
    int node = gid >> 5;
    if (node >= N) return;
    int d0 = (gid & 31) * 4;
    float4 v = *(const float4*)(X + (size_t)node * D + d0);
    float4 sc = *(const float4*)(scale + d0);
    float4 sh = *(const float4*)(shift + d0);
    float4 o;
    o.x = v.x * sc.x + sh.x;
    o.y = v.y * sc.y + sh.y;
    o.z = v.z * sc.z + sh.z;
    o.w = v.w * sc.w + sh.w;
    if (mode == 0) {
        ushort4 ob;
        ob.x = f2bf(fmaxf(o.x, 0.f));
        ob.y = f2bf(fmaxf(o.y, 0.f));
        ob.z = f2bf(fmaxf(o.z, 0.f));
        ob.w = f2bf(fmaxf(o.w, 0.f));
        *(ushort4*)(Yb + (size_t)node * D + d0) = ob;
    } else {
        *(float4*)(Yf + (size_t)node * D + d0) = o;
    }
}

// ---------------------------------------------------------------------------
extern "C" void kernel_launch(void* const* d_in, const int* in_sizes, int n_in,
                              void* d_out, int out_size, void* d_ws, size_t ws_size,
                              hipStream_t stream) {
    const int*   x        = (const int*)d_in[0];
    const int*   z        = (const int*)d_in[1];
    const int*   ei       = (const int*)d_in[2];
    const int*   ea       = (const int*)d_in[3];
    const float* atom_emb = (const float*)d_in[4];
    const float* z_emb    = (const float*)d_in[5];
    const float* bond_emb = (const float*)d_in[6];
    const float* eps      = (const float*)d_in[7];
    const float* W1       = (const float*)d_in[8];
    const float* b1       = (const float*)d_in[9];
    const float* g1       = (const float*)d_in[10];
    const float* be1      = (const float*)d_in[11];
    const float* W2       = (const float*)d_in[12];
    const float* b2       = (const float*)d_in[13];
    const float* bng      = (const float*)d_in[14];
    const float* bnb      = (const float*)d_in[15];

    const int N = in_sizes[1];
    const int E = in_sizes[3] / 3;

    float* h = (float*)d_out;  // final [N,128] fp32

    const int ngb = (N + 63) / 64;  // GEMM grid (same for both GEMMs)

    char* ws = (char*)d_ws;
    size_t off = 0;
    auto alloc = [&](size_t bytes) { void* p = ws + off; off += (bytes + 255) & ~(size_t)255; return p; };
    unsigned short* pre_bf = (unsigned short*)alloc((size_t)N * D * 2);      // 25.6 MB
    unsigned short* extra  = (unsigned short*)alloc((size_t)N * D * 2);      // 25.6 MB (out2 tail)
    (void)extra;
    float* out2 = (float*)pre_bf;                                            // spans pre_bf+extra
    unsigned short* out1_bf = (unsigned short*)alloc((size_t)N * 2 * D * 2); // 51.2 MB
    unsigned short* hb      = (unsigned short*)alloc((size_t)N * D * 2);     // 25.6 MB
    int* offsets = (int*)alloc((size_t)(N + 1) * 4);
    int* bucket  = (int*)alloc((size_t)E * 4);
    int* payload = (int*)alloc((size_t)E * 4);
    float* stats = (float*)alloc(1024 * 4);
    int* spart   = (int*)alloc(128 * 4);
    float* partial1 = (float*)alloc((size_t)ngb * 512 * 4);  // 3.2 MB
    float* partial2 = (float*)alloc((size_t)ngb * 256 * 4);  // 1.6 MB
    unsigned short* w1p  = (unsigned short*)alloc((size_t)2 * D * 2 * D * 2);
    unsigned short* w2p  = (unsigned short*)alloc((size_t)2 * 2 * D * D * 2);
    unsigned short* comb = (unsigned short*)alloc((size_t)2 * 216 * D * 2);
    // transient: counts/cursor alias out1_bf (dead until first GEMM1 write)
    int* counts = (int*)out1_bf;
    int* cursor = counts + N;

    float* scale1 = stats;          // 256
    float* shift1 = stats + 256;    // 256
    float* scale2 = stats + 512;    // 128
    float* shift2 = stats + 640;    // 128

    const float invN = 1.0f / (float)N;
    const int nb = (N + 1023) / 1024;
    const int SLICED_BLOCKS = 512;            // 64 groups x 8 slices
    const int SLICED_STRIDE = 64 * 256;

    // --- CSR build (layer-invariant) + one-time precomputes ---
    hipMemsetAsync(counts, 0, (size_t)N * 2 * sizeof(int), stream);
    payload_kernel<<<(E + 255) / 256, 256, 0, stream>>>(ei, ea, payload, E);
    hist_sliced_kernel<<<SLICED_BLOCKS, 256, 0, stream>>>(ei, counts, E, N, SLICED_STRIDE);
    scan_p1_kernel<<<nb, 256, 0, stream>>>(counts, spart, N);
    scan_p2_kernel<<<1, 128, 0, stream>>>(spart, nb);
    scan_p3_kernel<<<nb, 256, 0, stream>>>(counts, spart, offsets, N);
    fill_sliced_kernel<<<SLICED_BLOCKS, 256, 0, stream>>>(ei, payload, offsets, cursor, bucket,
                                                          E, N, SLICED_STRIDE);

    node_init_kernel<<<(N * 32 + 255) / 256, 256, 0, stream>>>(x, z, atom_emb, z_emb, hb, N);
    comb_kernel<<<dim3((216 * D + 255) / 256, 2), 256, 0, stream>>>(bond_emb, comb);
    pack_w_kernel<<<dim3((D * 2 * D + 255) / 256, 2), 256, 0, stream>>>(W1, w1p, D * 2 * D, 8);
    pack_w_kernel<<<dim3((2 * D * D + 255) / 256, 2), 256, 0, stream>>>(W2, w2p, 2 * D * D, 7);

    for (int l = 0; l < 2; ++l) {
        gather_reduce_kernel<<<(N * 16 + 255) / 256, 256, 0, stream>>>(
            offsets, bucket, comb + (size_t)l * 216 * D, hb, eps + l, pre_bf, N);

        mfma_gemm_kernel<128, 256, 0, 1><<<ngb, 256, 0, stream>>>(
            pre_bf, w1p + (size_t)l * D * 2 * D, b1 + (size_t)l * 2 * D,
            nullptr, nullptr, out1_bf, nullptr, partial1, N);
        reduce_stats_kernel<256><<<256, 256, 0, stream>>>(
            partial1, ngb, g1 + (size_t)l * 2 * D, be1 + (size_t)l * 2 * D,
            scale1, shift1, invN);

        mfma_gemm_kernel<256, 128, 1, 0><<<ngb, 256, 0, stream>>>(
            out1_bf, w2p + (size_t)l * 2 * D * D, b2 + (size_t)l * D,
            scale1, shift1, nullptr, out2, partial2, N);
        reduce_stats_kernel<128><<<128, 256, 0, stream>>>(
            partial2, ngb, bng + (size_t)l * D, bnb + (size_t)l * D,
            scale2, shift2, invN);

        bn_apply_kernel<<<(N * 32 + 255) / 256, 256, 0, stream>>>(out2, h, hb, scale2, shift2,
                                                                  N, l == 0 ? 0 : 1);
    }
}